// Round 15
// baseline (638.174 us; speedup 1.0000x reference)
//
#include <hip/hip_runtime.h>
#include <math.h>

#define BNS 0.9999950000374997f  /* 1/sqrt(1+1e-5) */

typedef short s8v __attribute__((ext_vector_type(8)));
typedef float f4v __attribute__((ext_vector_type(4)));

// ---------------------------------------------------------------- utilities
static __device__ __forceinline__ float wredf(float v) {
    #pragma unroll
    for (int o = 32; o; o >>= 1) v += __shfl_xor(v, o);
    return v;
}

static __device__ __forceinline__ unsigned short f2bf(float f) {
    unsigned int u = __float_as_uint(f);
    u = (u + 0x7fffu + ((u >> 16) & 1u)) >> 16;  // RNE
    return (unsigned short)u;
}

static __device__ __forceinline__ float bf2f(unsigned short b) {
    return __uint_as_float((unsigned int)b << 16);
}

static __device__ __forceinline__ f4v mfma16(s8v a, s8v b, f4v c) {
    return __builtin_amdgcn_mfma_f32_16x16x32_bf16(a, b, c, 0, 0, 0);
}

// ---------------------------------------------------------------- min of dst
__global__ void k_min(const int* __restrict__ d, int E, int* __restrict__ mn) {
    int i = blockIdx.x * blockDim.x + threadIdx.x;
    int v = 0x7FFFFFFF;
    for (; i < E; i += gridDim.x * blockDim.x) v = min(v, d[i]);
    #pragma unroll
    for (int o = 32; o; o >>= 1) v = min(v, __shfl_xor(v, o));
    if ((threadIdx.x & 63) == 0) atomicMin(mn, v);
}

// ---------------------------------------------------------------- bucket histogram (LDS-aggregated; few global atomics)
#define BC_CHUNK 2048
__global__ __launch_bounds__(256) void k_bcount(
        const int* __restrict__ dst, const int* __restrict__ src,
        const int* __restrict__ minbuf, int E, int nbD, int nbS,
        int* __restrict__ bcD, int* __restrict__ bcS) {
    __shared__ int hD[256];
    __shared__ int hS[1024];
    int tid = threadIdx.x;
    int mn = minbuf[0];
    int base = blockIdx.x * BC_CHUNK;
    int limit = min(base + BC_CHUNK, E);
    for (int i = tid; i < nbD; i += 256) hD[i] = 0;
    for (int i = tid; i < nbS; i += 256) hS[i] = 0;
    __syncthreads();
    for (int e = base + tid; e < limit; e += 256) {
        atomicAdd(&hD[(dst[e] - mn) >> 7], 1);
        atomicAdd(&hS[src[e] >> 7], 1);
    }
    __syncthreads();
    for (int i = tid; i < nbD; i += 256) { int c = hD[i]; if (c) atomicAdd(&bcD[i], c); }
    for (int i = tid; i < nbS; i += 256) { int c = hS[i]; if (c) atomicAdd(&bcS[i], c); }
}

// ---------------------------------------------------------------- small scan (single block; bucket counts <=1024)
__global__ __launch_bounds__(1024) void k_scan(const int* __restrict__ cnt, int n,
                                               int* __restrict__ rowptr) {
    __shared__ int wsum[16];
    __shared__ int carry;
    int tid = threadIdx.x, lane = tid & 63, wv = tid >> 6;
    if (tid == 0) carry = 0;
    __syncthreads();
    for (int base = 0; base < n; base += 1024) {
        int i = base + tid;
        int v = (i < n) ? cnt[i] : 0;
        int x = v;
        #pragma unroll
        for (int o = 1; o < 64; o <<= 1) { int t = __shfl_up(x, o); if (lane >= o) x += t; }
        if (lane == 63) wsum[wv] = x;
        __syncthreads();
        if (tid < 16) {
            int s = wsum[tid];
            #pragma unroll
            for (int o = 1; o < 16; o <<= 1) { int t = __shfl_up(s, o); if (tid >= o) s += t; }
            wsum[tid] = s;
        }
        __syncthreads();
        int woff = (wv == 0) ? 0 : wsum[wv - 1];
        int excl = carry + woff + x - v;
        if (i < n) rowptr[i] = excl;
        __syncthreads();
        if (tid == 1023) carry = carry + wsum[15];
        __syncthreads();
    }
    if (tid == 0) rowptr[n] = carry;
}

// ---------------------------------------------------------------- bucket cursor init: cur = copy of bucket bases
__global__ void k_curinit(const int* __restrict__ bbD, const int* __restrict__ bbS,
                          int nbD, int nbS,
                          int* __restrict__ curD, int* __restrict__ curS) {
    int i = blockIdx.x * blockDim.x + threadIdx.x;
    if (i < nbD) curD[i] = bbD[i];
    if (i < nbS) curS[i] = bbS[i];
}

// ---------------------------------------------------------------- phase A: bucket partition with run reservation
#define PART_CHUNK 2048
__global__ __launch_bounds__(256) void k_part(
        const int* __restrict__ dst, const int* __restrict__ src,
        const float* __restrict__ norm, const int* __restrict__ minbuf, int E,
        int nbD, int nbS, int* __restrict__ curD, int* __restrict__ curS,
        int2* __restrict__ tmpD, int2* __restrict__ tmpS) {
    __shared__ int histD[256];
    __shared__ int histS[1024];
    int tid = threadIdx.x;
    int mn = minbuf[0];
    int base = blockIdx.x * PART_CHUNK;
    int limit = min(base + PART_CHUNK, E);
    for (int i = tid; i < nbD; i += 256) histD[i] = 0;
    for (int i = tid; i < nbS; i += 256) histS[i] = 0;
    __syncthreads();
    for (int e = base + tid; e < limit; e += 256) {
        int d = dst[e] - mn;
        int s = src[e];
        atomicAdd(&histD[d >> 7], 1);
        atomicAdd(&histS[s >> 7], 1);
    }
    __syncthreads();
    for (int i = tid; i < nbD; i += 256) {
        int c = histD[i];
        histD[i] = c ? atomicAdd(&curD[i], c) : 0;
    }
    for (int i = tid; i < nbS; i += 256) {
        int c = histS[i];
        histS[i] = c ? atomicAdd(&curS[i], c) : 0;
    }
    __syncthreads();
    for (int e = base + tid; e < limit; e += 256) {
        int d = dst[e] - mn;
        int s = src[e];
        int w = __float_as_int(norm[e]);
        int pD = atomicAdd(&histD[d >> 7], 1);
        tmpD[pD] = make_int2(((d & 127) << 25) | s, w);
        int pS = atomicAdd(&histS[s >> 7], 1);
        tmpS[pS] = make_int2(((s & 127) << 25) | d, w);
    }
}

// ---------------------------------------------------------------- phase B: per-bucket rowptr build + CSR placement
__global__ __launch_bounds__(256) void k_place(
        const int2* __restrict__ tmp, const int* __restrict__ bb, int nrows, int nbuckets,
        int2* __restrict__ pairs, int* __restrict__ rowptr) {
    int b = blockIdx.x;
    int r0 = b << 7;
    int tid = threadIdx.x, lane = tid & 63, wvi = tid >> 6;
    __shared__ int cnt[128];
    __shared__ int cur[128];
    __shared__ int ws[4];
    if (tid < 128) cnt[tid] = 0;
    __syncthreads();
    int beg = bb[b], end = bb[b + 1];
    for (int p = beg + tid; p < end; p += 256)
        atomicAdd(&cnt[((unsigned)tmp[p].x) >> 25], 1);
    __syncthreads();
    int c = (tid < 128) ? cnt[tid] : 0;
    int x = c;
    #pragma unroll
    for (int o = 1; o < 64; o <<= 1) { int t = __shfl_up(x, o); if (lane >= o) x += t; }
    if (lane == 63) ws[wvi] = x;
    __syncthreads();
    if (tid < 128) {
        int excl = x - c + ((wvi == 1) ? ws[0] : 0);
        int rpv = beg + excl;
        if (r0 + tid < nrows) rowptr[r0 + tid] = rpv;
        cur[tid] = rpv;
    }
    if (b == 0 && tid == 0) rowptr[nrows] = bb[nbuckets];
    __syncthreads();
    for (int p = beg + tid; p < end; p += 256) {
        int2 en = tmp[p];
        int l = ((unsigned)en.x) >> 25;
        int pos = atomicAdd(&cur[l], 1);
        pairs[pos] = make_int2(en.x & 0x1FFFFFF, en.y);
    }
}

// ---------------------------------------------------------------- weight prep: fp32 [K][Nn] -> FRAGMENT-MAJOR bf16 hi/lo
// Element (k,n) -> fragment (ks=k/32, nt=n/16), lane = ((k%32)/8)*16 + n%16, j = k%8.
__global__ void k_prepT(const float* __restrict__ in, int nmat, int K, int Nn,
                        unsigned short* __restrict__ oh, unsigned short* __restrict__ ol) {
    int total = nmat * K * Nn;
    int ntile = Nn >> 4;
    for (int i = blockIdx.x * blockDim.x + threadIdx.x; i < total; i += gridDim.x * blockDim.x) {
        int m = i / (K * Nn), r = i % (K * Nn);
        int k = r / Nn, n = r % Nn;
        float v = in[i];
        unsigned short hb = f2bf(v);
        float lo = v - bf2f(hb);
        int ks = k >> 5, g = (k >> 3) & 3, j = k & 7;
        int nt = n >> 4, rm = n & 15;
        size_t o = (size_t)m * K * Nn + ((size_t)(ks * ntile + nt) * 64 + g * 16 + rm) * 8 + j;
        oh[o] = hb;
        ol[o] = f2bf(lo);
    }
}

// ---------------------------------------------------------------- row prep: center_scale -> dest fp32, then preop->LN->bf16 A
// quarter-wave (16 lanes) per row; 16 rows/block.
__global__ __launch_bounds__(256) void k_rowprep(
        const float* __restrict__ in, int S,
        const float* __restrict__ stats,   // null: skip center_scale
        float* __restrict__ dest,          // null: skip fp32 output
        int preop,
        const float* __restrict__ lng, const float* __restrict__ lnb,
        unsigned short* __restrict__ aln) {
    int lane = threadIdx.x & 63, wv = threadIdx.x >> 6;
    int sub = lane >> 4, l16 = lane & 15;
    int row = blockIdx.x * 16 + wv * 4 + sub;
    if (row >= S) return;
    const float* rp = in + (size_t)row * 128 + l16 * 8;
    float4 p0 = *(const float4*)rp;
    float4 p1 = *(const float4*)(rp + 4);
    float v[8] = {p0.x,p0.y,p0.z,p0.w,p1.x,p1.y,p1.z,p1.w};
    if (stats) {
        float inv = stats[128];
        const float4 m0 = *(const float4*)(stats + l16 * 8);
        const float4 m1 = *(const float4*)(stats + l16 * 8 + 4);
        float mu[8] = {m0.x,m0.y,m0.z,m0.w,m1.x,m1.y,m1.z,m1.w};
        #pragma unroll
        for (int j = 0; j < 8; j++) v[j] = (v[j] - mu[j]) * inv;
        if (dest) {
            float* dp = dest + (size_t)row * 128 + l16 * 8;
            *(float4*)dp       = make_float4(v[0], v[1], v[2], v[3]);
            *(float4*)(dp + 4) = make_float4(v[4], v[5], v[6], v[7]);
        }
    }
    float s = 0.f, q = 0.f;
    #pragma unroll
    for (int j = 0; j < 8; j++) {
        float x = v[j];
        if (preop) x = fmaxf(x * BNS, 0.f);
        v[j] = x;
        s += x; q += x * x;
    }
    #pragma unroll
    for (int o = 1; o < 16; o <<= 1) { s += __shfl_xor(s, o); q += __shfl_xor(q, o); }
    float m = s * (1.f / 128.f);
    float var = q * (1.f / 128.f) - m * m;
    float rs = rsqrtf(var + 1e-5f);
    const float4 g0 = *(const float4*)(lng + l16 * 8);
    const float4 g1 = *(const float4*)(lng + l16 * 8 + 4);
    const float4 b0 = *(const float4*)(lnb + l16 * 8);
    const float4 b1 = *(const float4*)(lnb + l16 * 8 + 4);
    float gg[8] = {g0.x,g0.y,g0.z,g0.w,g1.x,g1.y,g1.z,g1.w};
    float bb[8] = {b0.x,b0.y,b0.z,b0.w,b1.x,b1.y,b1.z,b1.w};
    s8v o;
    #pragma unroll
    for (int j = 0; j < 8; j++)
        o[j] = (short)f2bf((v[j] - m) * rs * gg[j] + bb[j]);
    *(s8v*)(aln + (size_t)row * 128 + l16 * 8) = o;
}

// ---------------------------------------------------------------- MFMA matmul, bf16 A planes (prepacked), fragment-major B
// NSPLIT=0: 32 rows/block, 2 m-waves x 2 n-waves, NT=4   (large S)
// NSPLIT=1: 16 rows/block, 4 n-waves, NT=2               (small S)
// DEC=0 (enc): A=hi only; acch=ah*bh, accl=ah*bl; bf16 out.
// DEC=1 (dec): A=hi+lo;  accl+=al*bh; fp32 out + banked stats[16][132].
template<int NSPLIT, int DEC>
__global__ __launch_bounds__(256, 6) void k_mm16(
        const unsigned short* __restrict__ ainh, const unsigned short* __restrict__ ainl,
        int S,
        const unsigned short* __restrict__ wth, const unsigned short* __restrict__ wtl,
        const float* __restrict__ bias, void* __restrict__ outv,
        float* __restrict__ stats) {
    int lane = threadIdx.x & 63, wv = threadIdx.x >> 6;
    int g = lane >> 4;          // k-group 0..3
    int rm = lane & 15;         // A-row within tile / C-col
    constexpr int NT = NSPLIT ? 2 : 4;
    int rbase, nt0;
    if (NSPLIT) { rbase = blockIdx.x * 16;                  nt0 = wv * 2; }
    else        { rbase = blockIdx.x * 32 + (wv >> 1) * 16; nt0 = (wv & 1) * 4; }
    int row = rbase + rm;
    bool ok = row < S;

    s8v ah[4], al[4];
    {
        const unsigned short* ap = ainh + (size_t)row * 128 + g * 8;
        const unsigned short* lp = DEC ? (ainl + (size_t)row * 128 + g * 8) : ap;
        #pragma unroll
        for (int ks = 0; ks < 4; ks++) {
            if (ok) {
                ah[ks] = *(const s8v*)(ap + ks * 32);
                if (DEC) al[ks] = *(const s8v*)(lp + ks * 32);
            } else {
                ah[ks] = (s8v){0,0,0,0,0,0,0,0};
                if (DEC) al[ks] = (s8v){0,0,0,0,0,0,0,0};
            }
        }
    }

    f4v acch[NT] = {};
    f4v accl[NT] = {};
    #pragma unroll
    for (int ks = 0; ks < 4; ks++) {
        s8v bh[NT], bl[NT];
        #pragma unroll
        for (int ntl = 0; ntl < NT; ntl++) {
            size_t o = ((size_t)(ks * 8 + nt0 + ntl) * 64 + lane) * 8;  // fragment-major, NTILE=8
            bh[ntl] = *(const s8v*)(wth + o);
            bl[ntl] = *(const s8v*)(wtl + o);
        }
        #pragma unroll
        for (int ntl = 0; ntl < NT; ntl++)
            acch[ntl] = mfma16(ah[ks], bh[ntl], acch[ntl]);
        #pragma unroll
        for (int ntl = 0; ntl < NT; ntl++)
            accl[ntl] = mfma16(ah[ks], bl[ntl], accl[ntl]);
        if (DEC) {
            #pragma unroll
            for (int ntl = 0; ntl < NT; ntl++)
                accl[ntl] = mfma16(al[ks], bh[ntl], accl[ntl]);
        }
    }

    __shared__ float cs[129];
    if (DEC && stats) {
        for (int i = threadIdx.x; i < 129; i += 256) cs[i] = 0.f;
        __syncthreads();
    }
    float myq = 0.f;
    #pragma unroll
    for (int ntl = 0; ntl < NT; ntl++) {
        int ntg = nt0 + ntl;
        float bb = bias[ntg * 16 + rm];
        float cp = 0.f;
        #pragma unroll
        for (int r = 0; r < 4; r++) {
            int orow = rbase + g * 4 + r;   // C row mapping
            float val = fmaxf(acch[ntl][r] + accl[ntl][r] + bb, 0.f);
            bool vok = orow < S;
            if (!DEC) {
                unsigned int bits = f2bf(val);
                unsigned int pb = (unsigned int)__shfl_xor((int)bits, 1);
                if (!(lane & 1) && vok) {
                    unsigned int word = bits | (pb << 16);
                    ((unsigned int*)outv)[((size_t)orow * 128 + ntg * 16 + rm) >> 1] = word;
                }
            } else {
                if (vok) ((float*)outv)[(size_t)orow * 128 + ntg * 16 + rm] = val;
                if (stats && vok) { cp += val; myq += val * val; }
            }
        }
        if (DEC && stats) {
            cp += __shfl_xor(cp, 16);
            cp += __shfl_xor(cp, 32);
            if (g == 0) atomicAdd(&cs[ntg * 16 + rm], cp);
        }
    }
    if (DEC && stats) {
        myq = wredf(myq);
        if (lane == 0) atomicAdd(&cs[128], myq);
        __syncthreads();
        float* sb = stats + (size_t)(blockIdx.x & 15) * 132;
        for (int i = threadIdx.x; i < 129; i += 256) {
            float v = cs[i];
            if (v != 0.f) atomicAdd(&sb[i], v);
        }
    }
}

// ---------------------------------------------------------------- CSR gather aggregation -> split hi/lo bf16 planes
// quarter-wave per row: 16 lanes x dwordx4 = 256 B row; 16 rows/block.
__global__ __launch_bounds__(256) void k_aggregate(
        const unsigned short* __restrict__ h, const int* __restrict__ rowptr,
        const int2* __restrict__ pairs,
        unsigned short* __restrict__ aggh, unsigned short* __restrict__ aggl, int T) {
    int lane = threadIdx.x & 63, wv = threadIdx.x >> 6;
    int sub = lane >> 4, l16 = lane & 15;
    int row = blockIdx.x * 16 + wv * 4 + sub;
    if (row >= T) return;
    int beg = rowptr[row], end = rowptr[row + 1];
    float a[8] = {0.f,0.f,0.f,0.f,0.f,0.f,0.f,0.f};
    #pragma unroll 4
    for (int p = beg; p < end; ++p) {
        int2 pr = pairs[p];
        const uint4 v = *(const uint4*)(h + (size_t)pr.x * 128 + l16 * 8);
        float w = __int_as_float(pr.y);
        a[0] = fmaf(w, __uint_as_float(v.x << 16),          a[0]);
        a[1] = fmaf(w, __uint_as_float(v.x & 0xffff0000u),  a[1]);
        a[2] = fmaf(w, __uint_as_float(v.y << 16),          a[2]);
        a[3] = fmaf(w, __uint_as_float(v.y & 0xffff0000u),  a[3]);
        a[4] = fmaf(w, __uint_as_float(v.z << 16),          a[4]);
        a[5] = fmaf(w, __uint_as_float(v.z & 0xffff0000u),  a[5]);
        a[6] = fmaf(w, __uint_as_float(v.w << 16),          a[6]);
        a[7] = fmaf(w, __uint_as_float(v.w & 0xffff0000u),  a[7]);
    }
    float invc = 1.f / fmaxf((float)(end - beg), 1.f);
    s8v oh, ol;
    #pragma unroll
    for (int j = 0; j < 8; j++) {
        float v = a[j] * invc;
        unsigned short hb = f2bf(v);
        oh[j] = (short)hb;
        ol[j] = (short)f2bf(v - bf2f(hb));
    }
    *(s8v*)(aggh + (size_t)row * 128 + l16 * 8) = oh;
    *(s8v*)(aggl + (size_t)row * 128 + l16 * 8) = ol;
}

// ---------------------------------------------------------------- finalize banked center_scale stats: mu[c], inv at [128]
__global__ void k_finalize(float* __restrict__ stats, int n) {
    int c = threadIdx.x;  // 128 threads
    float su = 0.f;
    #pragma unroll
    for (int b = 0; b < 16; b++) su += stats[b * 132 + c];
    float mu = su / (float)n;
    stats[c] = mu;
    float m2 = mu * mu;
    #pragma unroll
    for (int o = 32; o; o >>= 1) m2 += __shfl_xor(m2, o);
    __shared__ float ws2[2];
    if ((c & 63) == 0) ws2[c >> 6] = m2;
    __syncthreads();
    if (c == 0) {
        float qs = 0.f;
        #pragma unroll
        for (int b = 0; b < 16; b++) qs += stats[b * 132 + 128];
        float musq = ws2[0] + ws2[1];
        float msn = qs / (float)n - musq;  // mean ||x_i - mu||^2
        stats[128] = rsqrtf(1e-5f + msn);
    }
}

// ---------------------------------------------------------------- apply center_scale (conv4 tail only)
__global__ void k_apply(const float* __restrict__ in, const float* __restrict__ stats,
                        float* __restrict__ out, int n) {
    size_t i = ((size_t)blockIdx.x * blockDim.x + threadIdx.x) * 4;
    size_t tot = (size_t)n * 128;
    if (i >= tot) return;
    float inv = stats[128];
    int c = (int)(i & 127);
    float4 v = *(const float4*)(in + i);
    v.x = (v.x - stats[c])     * inv;
    v.y = (v.y - stats[c + 1]) * inv;
    v.z = (v.z - stats[c + 2]) * inv;
    v.w = (v.w - stats[c + 3]) * inv;
    *(float4*)(out + i) = v;
}

// ---------------------------------------------------------------- fused classifier: [M,384]@[384,256]+b1 -> LN -> relu -> @[256,2]+b2
// 16 rows/block, 4 waves x NT=4 cover all 256 cols; fragment-major W1; SC tile in LDS.
__global__ __launch_bounds__(256) void k_cls(
        const float* __restrict__ e0, const float* __restrict__ e1, const float* __restrict__ e2,
        const unsigned short* __restrict__ wth, const unsigned short* __restrict__ wtl,
        const float* __restrict__ b1,
        const float* __restrict__ lng, const float* __restrict__ lnb,
        const float* __restrict__ W2, const float* __restrict__ b2,
        float* __restrict__ out, int M) {
    __shared__ float SC[16 * 260];
    int lane = threadIdx.x & 63, wv = threadIdx.x >> 6;
    int g = lane >> 4, rm = lane & 15;
    int rbase = blockIdx.x * 16;
    int nt0 = wv * 4;
    int row = rbase + rm;
    bool ok = row < M;

    f4v acch[4] = {};
    f4v accl[4] = {};
    #pragma unroll
    for (int ks = 0; ks < 12; ks++) {
        const float* src = (ks < 4) ? e0 : (ks < 8) ? e1 : e2;
        const float* rp = src + (size_t)row * 128 + (ks & 3) * 32 + g * 8;
        float4 p0 = make_float4(0.f,0.f,0.f,0.f), p1 = make_float4(0.f,0.f,0.f,0.f);
        if (ok) { p0 = *(const float4*)rp; p1 = *(const float4*)(rp + 4); }
        float t[8] = {p0.x,p0.y,p0.z,p0.w,p1.x,p1.y,p1.z,p1.w};
        s8v ah, al;
        #pragma unroll
        for (int j = 0; j < 8; j++) {
            unsigned short hb = f2bf(t[j]);
            ah[j] = (short)hb;
            al[j] = (short)f2bf(t[j] - bf2f(hb));
        }
        s8v bh[4], bl[4];
        #pragma unroll
        for (int ntl = 0; ntl < 4; ntl++) {
            size_t o = ((size_t)(ks * 16 + nt0 + ntl) * 64 + lane) * 8;  // fragment-major, NTILE=16
            bh[ntl] = *(const s8v*)(wth + o);
            bl[ntl] = *(const s8v*)(wtl + o);
        }
        #pragma unroll
        for (int ntl = 0; ntl < 4; ntl++) acch[ntl] = mfma16(ah, bh[ntl], acch[ntl]);
        #pragma unroll
        for (int ntl = 0; ntl < 4; ntl++) accl[ntl] = mfma16(al, bh[ntl], accl[ntl]);
        #pragma unroll
        for (int ntl = 0; ntl < 4; ntl++) accl[ntl] = mfma16(ah, bl[ntl], accl[ntl]);
    }

    // stage SC tile (rows local 0..15, cols 0..255) in LDS
    #pragma unroll
    for (int ntl = 0; ntl < 4; ntl++) {
        int col = (nt0 + ntl) * 16 + rm;
        float bb = b1[col];
        #pragma unroll
        for (int r = 0; r < 4; r++) {
            int lr = g * 4 + r;
            SC[lr * 260 + col] = acch[ntl][r] + accl[ntl][r] + bb;
        }
    }
    __syncthreads();

    // LN -> relu -> W2 per row (wave wv handles rows wv*4 .. wv*4+3)
    #pragma unroll
    for (int rr = 0; rr < 4; rr++) {
        int lr = wv * 4 + rr;
        int orow = rbase + lr;
        const float* sp = SC + lr * 260;
        float v0 = sp[lane], v1 = sp[lane + 64], v2 = sp[lane + 128], v3 = sp[lane + 192];
        float s = wredf(v0 + v1 + v2 + v3);
        float q = wredf(v0 * v0 + v1 * v1 + v2 * v2 + v3 * v3);
        float m = s * (1.f / 256.f);
        float var = q * (1.f / 256.f) - m * m;
        float rs = rsqrtf(var + 1e-5f);
        float h0 = fmaxf((v0 - m) * rs * lng[lane]       + lnb[lane],       0.f);
        float h1 = fmaxf((v1 - m) * rs * lng[lane + 64]  + lnb[lane + 64],  0.f);
        float h2 = fmaxf((v2 - m) * rs * lng[lane + 128] + lnb[lane + 128], 0.f);
        float h3 = fmaxf((v3 - m) * rs * lng[lane + 192] + lnb[lane + 192], 0.f);
        float p0 = h0 * W2[lane * 2]             + h1 * W2[(lane + 64) * 2]
                 + h2 * W2[(lane + 128) * 2]     + h3 * W2[(lane + 192) * 2];
        float p1 = h0 * W2[lane * 2 + 1]         + h1 * W2[(lane + 64) * 2 + 1]
                 + h2 * W2[(lane + 128) * 2 + 1] + h3 * W2[(lane + 192) * 2 + 1];
        p0 = wredf(p0);
        p1 = wredf(p1);
        if (lane == 0 && orow < M) {
            out[(size_t)orow * 2]     = p0 + b2[0];
            out[(size_t)orow * 2 + 1] = p1 + b2[1];
        }
    }
}

// ================================================================ host
extern "C" void kernel_launch(void* const* d_in, const int* in_sizes, int n_in,
                              void* d_out, int out_size, void* d_ws, size_t ws_size,
                              hipStream_t stream) {
    const float* x    = (const float*)d_in[0];
    const int*   srcN = (const int*)d_in[1];
    const int*   dstE = (const int*)d_in[2];
    const float* norm = (const float*)d_in[3];
    const float* elng = (const float*)d_in[4];
    const float* elnb = (const float*)d_in[5];
    const float* eW   = (const float*)d_in[6];
    const float* eB   = (const float*)d_in[7];
    const float* dW   = (const float*)d_in[8];
    const float* dB   = (const float*)d_in[9];
    const float* W1   = (const float*)d_in[10];
    const float* b1   = (const float*)d_in[11];
    const float* clng = (const float*)d_in[12];
    const float* clnb = (const float*)d_in[13];
    const float* W2   = (const float*)d_in[14];
    const float* b2   = (const float*)d_in[15];

    const int N = in_sizes[0] / 128;
    const int E = in_sizes[1];
    const int M = (out_size - N * 128) / 130;
    const int nbD = (M + 127) >> 7;
    const int nbS = (N + 127) >> 7;

    // workspace carve
    char* p = (char*)d_ws;
    auto carve = [&](size_t bytes) { void* q = (void*)p; p += ((bytes + 255) / 256) * 256; return q; };
    int*   minv  = (int*)carve(4);
    int*   bcD   = (int*)carve((size_t)nbD * 4);
    int*   bcS   = (int*)carve((size_t)nbS * 4);
    int*   bbD   = (int*)carve((size_t)(nbD + 1) * 4);
    int*   bbS   = (int*)carve((size_t)(nbS + 1) * 4);
    int*   curD  = (int*)carve((size_t)nbD * 4);
    int*   curS  = (int*)carve((size_t)nbS * 4);
    int*   rpM   = (int*)carve((size_t)(M + 1) * 4);
    int*   rpN   = (int*)carve((size_t)(N + 1) * 4);
    int2*  pairD = (int2*)carve((size_t)E * 8);
    int2*  pairS = (int2*)carve((size_t)E * 8);
    float* stats = (float*)carve(16 * 132 * 4);
    unsigned short* encTh = (unsigned short*)carve((size_t)5 * 16384 * 2);
    unsigned short* encTl = (unsigned short*)carve((size_t)5 * 16384 * 2);
    unsigned short* decTh = (unsigned short*)carve((size_t)5 * 16384 * 2);
    unsigned short* decTl = (unsigned short*)carve((size_t)5 * 16384 * 2);
    unsigned short* w1Th  = (unsigned short*)carve((size_t)384 * 256 * 2);
    unsigned short* w1Tl  = (unsigned short*)carve((size_t)384 * 256 * 2);
    float* hbuf  = (float*)carve((size_t)N * 128 * 4);            // dec fp32 out; hb16 overlay
    unsigned short* aggh = (unsigned short*)carve((size_t)N * 128 * 2);  // agg hi plane
    unsigned short* aggl = (unsigned short*)carve((size_t)N * 128 * 2);  // agg lo plane; aln16 overlay (disjoint windows)
    float* e0    = (float*)carve((size_t)M * 128 * 4);
    float* e1    = (float*)carve((size_t)M * 128 * 4);
    unsigned short* hb16  = (unsigned short*)hbuf;     // enc bf16 out; dead before dec writes hbuf
    unsigned short* aln16 = aggl;                      // LN'd bf16 A; live only while aggl dead
    int2*  tmpD = (int2*)e0;                           // bucket-grouped entries (graph build only)
    int2*  tmpS = (int2*)e1;

    float* outf      = (float*)d_out;
    float* score     = outf;                                   // [M,2]
    float* edge_feat = outf + (size_t)M * 2;                   // [M,128]
    float* node_feat = outf + (size_t)M * 2 + (size_t)M * 128; // [N,128]

    // ---- weight prep (transpose + split-bf16, fragment-major)
    k_prepT<<<320, 256, 0, stream>>>(eW, 5, 128, 128, encTh, encTl);
    k_prepT<<<320, 256, 0, stream>>>(dW, 5, 128, 128, decTh, decTl);
    k_prepT<<<384, 256, 0, stream>>>(W1, 1, 384, 256, w1Th, w1Tl);

    // ---- graph structure: bucket count -> bucket scan -> partition -> per-bucket rowptr+CSR place
    hipMemsetAsync(minv, 0x7f, 4, stream);
    hipMemsetAsync(bcD, 0, (size_t)nbD * 4, stream);
    hipMemsetAsync(bcS, 0, (size_t)nbS * 4, stream);
    k_min<<<256, 256, 0, stream>>>(dstE, E, minv);
    k_bcount<<<(E + BC_CHUNK - 1) / BC_CHUNK, 256, 0, stream>>>(dstE, srcN, minv, E, nbD, nbS, bcD, bcS);
    k_scan<<<1, 1024, 0, stream>>>(bcD, nbD, bbD);
    k_scan<<<1, 1024, 0, stream>>>(bcS, nbS, bbS);
    k_curinit<<<(max(nbD, nbS) + 255) / 256, 256, 0, stream>>>(bbD, bbS, nbD, nbS, curD, curS);
    k_part<<<(E + PART_CHUNK - 1) / PART_CHUNK, 256, 0, stream>>>(
        dstE, srcN, norm, minv, E, nbD, nbS, curD, curS, tmpD, tmpS);
    k_place<<<nbD, 256, 0, stream>>>(tmpD, bbD, M, nbD, pairD, rpM);
    k_place<<<nbS, 256, 0, stream>>>(tmpS, bbS, N, nbS, pairS, rpN);

    // ---- matmul dispatch helpers
    auto mmenc = [&](int rows, int k) {
        if (rows > 30000)
            k_mm16<0,0><<<(rows + 31) / 32, 256, 0, stream>>>(
                aln16, nullptr, rows, encTh + (size_t)k * 16384, encTl + (size_t)k * 16384,
                eB + (size_t)k * 128, hb16, nullptr);
        else
            k_mm16<1,0><<<(rows + 15) / 16, 256, 0, stream>>>(
                aln16, nullptr, rows, encTh + (size_t)k * 16384, encTl + (size_t)k * 16384,
                eB + (size_t)k * 128, hb16, nullptr);
    };
    auto mmdec = [&](int rows, int k) {
        if (rows > 30000)
            k_mm16<0,1><<<(rows + 31) / 32, 256, 0, stream>>>(
                aggh, aggl, rows, decTh + (size_t)k * 16384, decTl + (size_t)k * 16384,
                dB + (size_t)k * 128, hbuf, stats);
        else
            k_mm16<1,1><<<(rows + 15) / 16, 256, 0, stream>>>(
                aggh, aggl, rows, decTh + (size_t)k * 16384, decTl + (size_t)k * 16384,
                dB + (size_t)k * 128, hbuf, stats);
    };

    // ---- one half-conv: enc(bf16 A) -> CSR-mean agg (split hi/lo) -> dec(fused stats) -> rowprep tail
    auto conv = [&](int S, int T, int k, int v2e, float* dest) {
        mmenc(S, k);
        if (v2e)
            k_aggregate<<<(T + 15) / 16, 256, 0, stream>>>(hb16, rpM, pairD, aggh, aggl, T);
        else
            k_aggregate<<<(T + 15) / 16, 256, 0, stream>>>(hb16, rpN, pairS, aggh, aggl, T);
        hipMemsetAsync(stats, 0, 16 * 132 * 4, stream);
        mmdec(T, k);
        k_finalize<<<1, 128, 0, stream>>>(stats, T);
        if (k < 4) {
            // fused: center_scale -> dest (skipped if dead), then preop+LN+bf16 for conv k+1's enc A
            k_rowprep<<<(T + 15) / 16, 256, 0, stream>>>(
                hbuf, T, stats, dest, 1,
                elng + (size_t)(k + 1) * 128, elnb + (size_t)(k + 1) * 128, aln16);
        } else {
            size_t tot4 = ((size_t)T * 128) / 4;
            k_apply<<<(unsigned)((tot4 + 255) / 256), 256, 0, stream>>>(hbuf, stats, dest, T);
        }
    };

    // conv0's enc A from raw x (no preop, LN params k=0)
    k_rowprep<<<(N + 15) / 16, 256, 0, stream>>>(x, N, nullptr, nullptr, 0, elng, elnb, aln16);
    conv(N, M, 0, 1, e0);         // V2E0  (tail preps conv1's A at M rows)
    conv(M, N, 1, 0, nullptr);    // E2V0  (nf1 is dead — overwritten by conv3 before any read)
    conv(N, M, 2, 1, e1);         // V2E1
    conv(M, N, 3, 0, node_feat);  // E2V1 -> final node_feat
    conv(N, M, 4, 1, edge_feat);  // V2E2 -> final edge_feat (plain apply tail)

    k_cls<<<(M + 15) / 16, 256, 0, stream>>>(
        e0, e1, edge_feat, w1Th, w1Tl, b1, clng, clnb, W2, b2, score, M);
}

// Round 16
// 627.664 us; speedup vs baseline: 1.0167x; 1.0167x over previous
//
#include <hip/hip_runtime.h>
#include <math.h>

#define BNS 0.9999950000374997f  /* 1/sqrt(1+1e-5) */

typedef short s8v __attribute__((ext_vector_type(8)));
typedef float f4v __attribute__((ext_vector_type(4)));

// ---------------------------------------------------------------- utilities
static __device__ __forceinline__ float wredf(float v) {
    #pragma unroll
    for (int o = 32; o; o >>= 1) v += __shfl_xor(v, o);
    return v;
}

static __device__ __forceinline__ unsigned short f2bf(float f) {
    unsigned int u = __float_as_uint(f);
    u = (u + 0x7fffu + ((u >> 16) & 1u)) >> 16;  // RNE
    return (unsigned short)u;
}

static __device__ __forceinline__ float bf2f(unsigned short b) {
    return __uint_as_float((unsigned int)b << 16);
}

static __device__ __forceinline__ f4v mfma16(s8v a, s8v b, f4v c) {
    return __builtin_amdgcn_mfma_f32_16x16x32_bf16(a, b, c, 0, 0, 0);
}

// ---------------------------------------------------------------- min of dst
__global__ void k_min(const int* __restrict__ d, int E, int* __restrict__ mn) {
    int i = blockIdx.x * blockDim.x + threadIdx.x;
    int v = 0x7FFFFFFF;
    for (; i < E; i += gridDim.x * blockDim.x) v = min(v, d[i]);
    #pragma unroll
    for (int o = 32; o; o >>= 1) v = min(v, __shfl_xor(v, o));
    if ((threadIdx.x & 63) == 0) atomicMin(mn, v);
}

// ---------------------------------------------------------------- bucket histogram (256-row buckets; LDS-aggregated)
#define BC_CHUNK 4096
__global__ __launch_bounds__(256) void k_bcount(
        const int* __restrict__ dst, const int* __restrict__ src,
        const int* __restrict__ minbuf, int E, int nbD, int nbS,
        int* __restrict__ bcD, int* __restrict__ bcS) {
    __shared__ int hD[128];
    __shared__ int hS[512];
    int tid = threadIdx.x;
    int mn = minbuf[0];
    int base = blockIdx.x * BC_CHUNK;
    int limit = min(base + BC_CHUNK, E);
    for (int i = tid; i < nbD; i += 256) hD[i] = 0;
    for (int i = tid; i < nbS; i += 256) hS[i] = 0;
    __syncthreads();
    for (int e = base + tid; e < limit; e += 256) {
        atomicAdd(&hD[(dst[e] - mn) >> 8], 1);
        atomicAdd(&hS[src[e] >> 8], 1);
    }
    __syncthreads();
    for (int i = tid; i < nbD; i += 256) { int c = hD[i]; if (c) atomicAdd(&bcD[i], c); }
    for (int i = tid; i < nbS; i += 256) { int c = hS[i]; if (c) atomicAdd(&bcS[i], c); }
}

// ---------------------------------------------------------------- small scan (single block; bucket counts <=1024)
__global__ __launch_bounds__(1024) void k_scan(const int* __restrict__ cnt, int n,
                                               int* __restrict__ rowptr) {
    __shared__ int wsum[16];
    __shared__ int carry;
    int tid = threadIdx.x, lane = tid & 63, wv = tid >> 6;
    if (tid == 0) carry = 0;
    __syncthreads();
    for (int base = 0; base < n; base += 1024) {
        int i = base + tid;
        int v = (i < n) ? cnt[i] : 0;
        int x = v;
        #pragma unroll
        for (int o = 1; o < 64; o <<= 1) { int t = __shfl_up(x, o); if (lane >= o) x += t; }
        if (lane == 63) wsum[wv] = x;
        __syncthreads();
        if (tid < 16) {
            int s = wsum[tid];
            #pragma unroll
            for (int o = 1; o < 16; o <<= 1) { int t = __shfl_up(s, o); if (tid >= o) s += t; }
            wsum[tid] = s;
        }
        __syncthreads();
        int woff = (wv == 0) ? 0 : wsum[wv - 1];
        int excl = carry + woff + x - v;
        if (i < n) rowptr[i] = excl;
        __syncthreads();
        if (tid == 1023) carry = carry + wsum[15];
        __syncthreads();
    }
    if (tid == 0) rowptr[n] = carry;
}

// ---------------------------------------------------------------- bucket cursor init: cur = copy of bucket bases
__global__ void k_curinit(const int* __restrict__ bbD, const int* __restrict__ bbS,
                          int nbD, int nbS,
                          int* __restrict__ curD, int* __restrict__ curS) {
    int i = blockIdx.x * blockDim.x + threadIdx.x;
    if (i < nbD) curD[i] = bbD[i];
    if (i < nbS) curS[i] = bbS[i];
}

// ---------------------------------------------------------------- phase A: bucket partition with run reservation
// Entries packed: .x = (local_row<<24) | gather_row (local<256, gather<2^24).
#define PART_CHUNK 4096
__global__ __launch_bounds__(256) void k_part(
        const int* __restrict__ dst, const int* __restrict__ src,
        const float* __restrict__ norm, const int* __restrict__ minbuf, int E,
        int nbD, int nbS, int* __restrict__ curD, int* __restrict__ curS,
        int2* __restrict__ tmpD, int2* __restrict__ tmpS) {
    __shared__ int histD[128];
    __shared__ int histS[512];
    int tid = threadIdx.x;
    int mn = minbuf[0];
    int base = blockIdx.x * PART_CHUNK;
    int limit = min(base + PART_CHUNK, E);
    for (int i = tid; i < nbD; i += 256) histD[i] = 0;
    for (int i = tid; i < nbS; i += 256) histS[i] = 0;
    __syncthreads();
    for (int e = base + tid; e < limit; e += 256) {
        int d = dst[e] - mn;
        int s = src[e];
        atomicAdd(&histD[d >> 8], 1);
        atomicAdd(&histS[s >> 8], 1);
    }
    __syncthreads();
    for (int i = tid; i < nbD; i += 256) {
        int c = histD[i];
        histD[i] = c ? atomicAdd(&curD[i], c) : 0;
    }
    for (int i = tid; i < nbS; i += 256) {
        int c = histS[i];
        histS[i] = c ? atomicAdd(&curS[i], c) : 0;
    }
    __syncthreads();
    for (int e = base + tid; e < limit; e += 256) {
        int d = dst[e] - mn;
        int s = src[e];
        int w = __float_as_int(norm[e]);
        int pD = atomicAdd(&histD[d >> 8], 1);
        tmpD[pD] = make_int2(((d & 255) << 24) | s, w);
        int pS = atomicAdd(&histS[s >> 8], 1);
        tmpS[pS] = make_int2(((s & 255) << 24) | d, w);
    }
}

// ---------------------------------------------------------------- phase B: per-bucket (256 rows) rowptr build + CSR placement
__global__ __launch_bounds__(256) void k_place(
        const int2* __restrict__ tmp, const int* __restrict__ bb, int nrows, int nbuckets,
        int2* __restrict__ pairs, int* __restrict__ rowptr) {
    int b = blockIdx.x;
    int r0 = b << 8;
    int tid = threadIdx.x, lane = tid & 63, wvi = tid >> 6;
    __shared__ int cnt[256];
    __shared__ int cur[256];
    __shared__ int ws[4];
    cnt[tid] = 0;
    __syncthreads();
    int beg = bb[b], end = bb[b + 1];
    for (int p = beg + tid; p < end; p += 256)
        atomicAdd(&cnt[((unsigned)tmp[p].x) >> 24], 1);
    __syncthreads();
    int c = cnt[tid];
    int x = c;
    #pragma unroll
    for (int o = 1; o < 64; o <<= 1) { int t = __shfl_up(x, o); if (lane >= o) x += t; }
    if (lane == 63) ws[wvi] = x;
    __syncthreads();
    int woff = 0;
    for (int i = 0; i < wvi; i++) woff += ws[i];
    int rpv = beg + woff + x - c;
    if (r0 + tid < nrows) rowptr[r0 + tid] = rpv;
    cur[tid] = rpv;
    if (b == 0 && tid == 0) rowptr[nrows] = bb[nbuckets];
    __syncthreads();
    for (int p = beg + tid; p < end; p += 256) {
        int2 en = tmp[p];
        int l = ((unsigned)en.x) >> 24;
        int pos = atomicAdd(&cur[l], 1);
        pairs[pos] = make_int2(en.x & 0xFFFFFF, en.y);
    }
}

// ---------------------------------------------------------------- weight prep: fp32 [K][Nn] -> FRAGMENT-MAJOR bf16 hi/lo
// Element (k,n) -> fragment (ks=k/32, nt=n/16), lane = ((k%32)/8)*16 + n%16, j = k%8.
__global__ void k_prepT(const float* __restrict__ in, int nmat, int K, int Nn,
                        unsigned short* __restrict__ oh, unsigned short* __restrict__ ol) {
    int total = nmat * K * Nn;
    int ntile = Nn >> 4;
    for (int i = blockIdx.x * blockDim.x + threadIdx.x; i < total; i += gridDim.x * blockDim.x) {
        int m = i / (K * Nn), r = i % (K * Nn);
        int k = r / Nn, n = r % Nn;
        float v = in[i];
        unsigned short hb = f2bf(v);
        float lo = v - bf2f(hb);
        int ks = k >> 5, g = (k >> 3) & 3, j = k & 7;
        int nt = n >> 4, rm = n & 15;
        size_t o = (size_t)m * K * Nn + ((size_t)(ks * ntile + nt) * 64 + g * 16 + rm) * 8 + j;
        oh[o] = hb;
        ol[o] = f2bf(lo);
    }
}

// ---------------------------------------------------------------- row prep: center_scale -> dest fp32, then preop->LN->bf16 A
// quarter-wave (16 lanes) per row; 16 rows/block.
__global__ __launch_bounds__(256) void k_rowprep(
        const float* __restrict__ in, int S,
        const float* __restrict__ stats,   // null: skip center_scale
        float* __restrict__ dest,          // null: skip fp32 output
        int preop,
        const float* __restrict__ lng, const float* __restrict__ lnb,
        unsigned short* __restrict__ aln) {
    int lane = threadIdx.x & 63, wv = threadIdx.x >> 6;
    int sub = lane >> 4, l16 = lane & 15;
    int row = blockIdx.x * 16 + wv * 4 + sub;
    if (row >= S) return;
    const float* rp = in + (size_t)row * 128 + l16 * 8;
    float4 p0 = *(const float4*)rp;
    float4 p1 = *(const float4*)(rp + 4);
    float v[8] = {p0.x,p0.y,p0.z,p0.w,p1.x,p1.y,p1.z,p1.w};
    if (stats) {
        float inv = stats[128];
        const float4 m0 = *(const float4*)(stats + l16 * 8);
        const float4 m1 = *(const float4*)(stats + l16 * 8 + 4);
        float mu[8] = {m0.x,m0.y,m0.z,m0.w,m1.x,m1.y,m1.z,m1.w};
        #pragma unroll
        for (int j = 0; j < 8; j++) v[j] = (v[j] - mu[j]) * inv;
        if (dest) {
            float* dp = dest + (size_t)row * 128 + l16 * 8;
            *(float4*)dp       = make_float4(v[0], v[1], v[2], v[3]);
            *(float4*)(dp + 4) = make_float4(v[4], v[5], v[6], v[7]);
        }
    }
    float s = 0.f, q = 0.f;
    #pragma unroll
    for (int j = 0; j < 8; j++) {
        float x = v[j];
        if (preop) x = fmaxf(x * BNS, 0.f);
        v[j] = x;
        s += x; q += x * x;
    }
    #pragma unroll
    for (int o = 1; o < 16; o <<= 1) { s += __shfl_xor(s, o); q += __shfl_xor(q, o); }
    float m = s * (1.f / 128.f);
    float var = q * (1.f / 128.f) - m * m;
    float rs = rsqrtf(var + 1e-5f);
    const float4 g0 = *(const float4*)(lng + l16 * 8);
    const float4 g1 = *(const float4*)(lng + l16 * 8 + 4);
    const float4 b0 = *(const float4*)(lnb + l16 * 8);
    const float4 b1 = *(const float4*)(lnb + l16 * 8 + 4);
    float gg[8] = {g0.x,g0.y,g0.z,g0.w,g1.x,g1.y,g1.z,g1.w};
    float bb[8] = {b0.x,b0.y,b0.z,b0.w,b1.x,b1.y,b1.z,b1.w};
    s8v o;
    #pragma unroll
    for (int j = 0; j < 8; j++)
        o[j] = (short)f2bf((v[j] - m) * rs * gg[j] + bb[j]);
    *(s8v*)(aln + (size_t)row * 128 + l16 * 8) = o;
}

// ---------------------------------------------------------------- MFMA matmul, bf16 A planes (prepacked), fragment-major B
// NSPLIT=0: 32 rows/block, 2 m-waves x 2 n-waves, NT=4   (large S)
// NSPLIT=1: 16 rows/block, 4 n-waves, NT=2               (small S)
// DEC=0 (enc): A=hi only; acch=ah*bh, accl=ah*bl; bf16 out.
// DEC=1 (dec): A=hi+lo;  accl+=al*bh; fp32 out + banked stats[16][132].
template<int NSPLIT, int DEC>
__global__ __launch_bounds__(256, 6) void k_mm16(
        const unsigned short* __restrict__ ainh, const unsigned short* __restrict__ ainl,
        int S,
        const unsigned short* __restrict__ wth, const unsigned short* __restrict__ wtl,
        const float* __restrict__ bias, void* __restrict__ outv,
        float* __restrict__ stats) {
    int lane = threadIdx.x & 63, wv = threadIdx.x >> 6;
    int g = lane >> 4;          // k-group 0..3
    int rm = lane & 15;         // A-row within tile / C-col
    constexpr int NT = NSPLIT ? 2 : 4;
    int rbase, nt0;
    if (NSPLIT) { rbase = blockIdx.x * 16;                  nt0 = wv * 2; }
    else        { rbase = blockIdx.x * 32 + (wv >> 1) * 16; nt0 = (wv & 1) * 4; }
    int row = rbase + rm;
    bool ok = row < S;

    s8v ah[4], al[4];
    {
        const unsigned short* ap = ainh + (size_t)row * 128 + g * 8;
        const unsigned short* lp = DEC ? (ainl + (size_t)row * 128 + g * 8) : ap;
        #pragma unroll
        for (int ks = 0; ks < 4; ks++) {
            if (ok) {
                ah[ks] = *(const s8v*)(ap + ks * 32);
                if (DEC) al[ks] = *(const s8v*)(lp + ks * 32);
            } else {
                ah[ks] = (s8v){0,0,0,0,0,0,0,0};
                if (DEC) al[ks] = (s8v){0,0,0,0,0,0,0,0};
            }
        }
    }

    f4v acch[NT] = {};
    f4v accl[NT] = {};
    #pragma unroll
    for (int ks = 0; ks < 4; ks++) {
        s8v bh[NT], bl[NT];
        #pragma unroll
        for (int ntl = 0; ntl < NT; ntl++) {
            size_t o = ((size_t)(ks * 8 + nt0 + ntl) * 64 + lane) * 8;  // fragment-major, NTILE=8
            bh[ntl] = *(const s8v*)(wth + o);
            bl[ntl] = *(const s8v*)(wtl + o);
        }
        #pragma unroll
        for (int ntl = 0; ntl < NT; ntl++)
            acch[ntl] = mfma16(ah[ks], bh[ntl], acch[ntl]);
        #pragma unroll
        for (int ntl = 0; ntl < NT; ntl++)
            accl[ntl] = mfma16(ah[ks], bl[ntl], accl[ntl]);
        if (DEC) {
            #pragma unroll
            for (int ntl = 0; ntl < NT; ntl++)
                accl[ntl] = mfma16(al[ks], bh[ntl], accl[ntl]);
        }
    }

    __shared__ float cs[129];
    if (DEC && stats) {
        for (int i = threadIdx.x; i < 129; i += 256) cs[i] = 0.f;
        __syncthreads();
    }
    float myq = 0.f;
    #pragma unroll
    for (int ntl = 0; ntl < NT; ntl++) {
        int ntg = nt0 + ntl;
        float bb = bias[ntg * 16 + rm];
        float cp = 0.f;
        #pragma unroll
        for (int r = 0; r < 4; r++) {
            int orow = rbase + g * 4 + r;   // C row mapping
            float val = fmaxf(acch[ntl][r] + accl[ntl][r] + bb, 0.f);
            bool vok = orow < S;
            if (!DEC) {
                unsigned int bits = f2bf(val);
                unsigned int pb = (unsigned int)__shfl_xor((int)bits, 1);
                if (!(lane & 1) && vok) {
                    unsigned int word = bits | (pb << 16);
                    ((unsigned int*)outv)[((size_t)orow * 128 + ntg * 16 + rm) >> 1] = word;
                }
            } else {
                if (vok) ((float*)outv)[(size_t)orow * 128 + ntg * 16 + rm] = val;
                if (stats && vok) { cp += val; myq += val * val; }
            }
        }
        if (DEC && stats) {
            cp += __shfl_xor(cp, 16);
            cp += __shfl_xor(cp, 32);
            if (g == 0) atomicAdd(&cs[ntg * 16 + rm], cp);
        }
    }
    if (DEC && stats) {
        myq = wredf(myq);
        if (lane == 0) atomicAdd(&cs[128], myq);
        __syncthreads();
        float* sb = stats + (size_t)(blockIdx.x & 15) * 132;
        for (int i = threadIdx.x; i < 129; i += 256) {
            float v = cs[i];
            if (v != 0.f) atomicAdd(&sb[i], v);
        }
    }
}

// ---------------------------------------------------------------- CSR gather aggregation -> split hi/lo bf16 planes
// quarter-wave per row: 16 lanes x dwordx4 = 256 B row; 16 rows/block.
__global__ __launch_bounds__(256) void k_aggregate(
        const unsigned short* __restrict__ h, const int* __restrict__ rowptr,
        const int2* __restrict__ pairs,
        unsigned short* __restrict__ aggh, unsigned short* __restrict__ aggl, int T) {
    int lane = threadIdx.x & 63, wv = threadIdx.x >> 6;
    int sub = lane >> 4, l16 = lane & 15;
    int row = blockIdx.x * 16 + wv * 4 + sub;
    if (row >= T) return;
    int beg = rowptr[row], end = rowptr[row + 1];
    float a[8] = {0.f,0.f,0.f,0.f,0.f,0.f,0.f,0.f};
    #pragma unroll 4
    for (int p = beg; p < end; ++p) {
        int2 pr = pairs[p];
        const uint4 v = *(const uint4*)(h + (size_t)pr.x * 128 + l16 * 8);
        float w = __int_as_float(pr.y);
        a[0] = fmaf(w, __uint_as_float(v.x << 16),          a[0]);
        a[1] = fmaf(w, __uint_as_float(v.x & 0xffff0000u),  a[1]);
        a[2] = fmaf(w, __uint_as_float(v.y << 16),          a[2]);
        a[3] = fmaf(w, __uint_as_float(v.y & 0xffff0000u),  a[3]);
        a[4] = fmaf(w, __uint_as_float(v.z << 16),          a[4]);
        a[5] = fmaf(w, __uint_as_float(v.z & 0xffff0000u),  a[5]);
        a[6] = fmaf(w, __uint_as_float(v.w << 16),          a[6]);
        a[7] = fmaf(w, __uint_as_float(v.w & 0xffff0000u),  a[7]);
    }
    float invc = 1.f / fmaxf((float)(end - beg), 1.f);
    s8v oh, ol;
    #pragma unroll
    for (int j = 0; j < 8; j++) {
        float v = a[j] * invc;
        unsigned short hb = f2bf(v);
        oh[j] = (short)hb;
        ol[j] = (short)f2bf(v - bf2f(hb));
    }
    *(s8v*)(aggh + (size_t)row * 128 + l16 * 8) = oh;
    *(s8v*)(aggl + (size_t)row * 128 + l16 * 8) = ol;
}

// ---------------------------------------------------------------- finalize banked center_scale stats: mu[c], inv at [128]
__global__ void k_finalize(float* __restrict__ stats, int n) {
    int c = threadIdx.x;  // 128 threads
    float su = 0.f;
    #pragma unroll
    for (int b = 0; b < 16; b++) su += stats[b * 132 + c];
    float mu = su / (float)n;
    stats[c] = mu;
    float m2 = mu * mu;
    #pragma unroll
    for (int o = 32; o; o >>= 1) m2 += __shfl_xor(m2, o);
    __shared__ float ws2[2];
    if ((c & 63) == 0) ws2[c >> 6] = m2;
    __syncthreads();
    if (c == 0) {
        float qs = 0.f;
        #pragma unroll
        for (int b = 0; b < 16; b++) qs += stats[b * 132 + 128];
        float musq = ws2[0] + ws2[1];
        float msn = qs / (float)n - musq;  // mean ||x_i - mu||^2
        stats[128] = rsqrtf(1e-5f + msn);
    }
}

// ---------------------------------------------------------------- apply center_scale (conv4 tail only)
__global__ void k_apply(const float* __restrict__ in, const float* __restrict__ stats,
                        float* __restrict__ out, int n) {
    size_t i = ((size_t)blockIdx.x * blockDim.x + threadIdx.x) * 4;
    size_t tot = (size_t)n * 128;
    if (i >= tot) return;
    float inv = stats[128];
    int c = (int)(i & 127);
    float4 v = *(const float4*)(in + i);
    v.x = (v.x - stats[c])     * inv;
    v.y = (v.y - stats[c + 1]) * inv;
    v.z = (v.z - stats[c + 2]) * inv;
    v.w = (v.w - stats[c + 3]) * inv;
    *(float4*)(out + i) = v;
}

// ---------------------------------------------------------------- fused classifier: [M,384]@[384,256]+b1 -> LN -> relu -> @[256,2]+b2
// 16 rows/block, 4 waves x NT=4 cover all 256 cols; fragment-major W1; SC tile in LDS.
__global__ __launch_bounds__(256) void k_cls(
        const float* __restrict__ e0, const float* __restrict__ e1, const float* __restrict__ e2,
        const unsigned short* __restrict__ wth, const unsigned short* __restrict__ wtl,
        const float* __restrict__ b1,
        const float* __restrict__ lng, const float* __restrict__ lnb,
        const float* __restrict__ W2, const float* __restrict__ b2,
        float* __restrict__ out, int M) {
    __shared__ float SC[16 * 260];
    int lane = threadIdx.x & 63, wv = threadIdx.x >> 6;
    int g = lane >> 4, rm = lane & 15;
    int rbase = blockIdx.x * 16;
    int nt0 = wv * 4;
    int row = rbase + rm;
    bool ok = row < M;

    f4v acch[4] = {};
    f4v accl[4] = {};
    #pragma unroll
    for (int ks = 0; ks < 12; ks++) {
        const float* src = (ks < 4) ? e0 : (ks < 8) ? e1 : e2;
        const float* rp = src + (size_t)row * 128 + (ks & 3) * 32 + g * 8;
        float4 p0 = make_float4(0.f,0.f,0.f,0.f), p1 = make_float4(0.f,0.f,0.f,0.f);
        if (ok) { p0 = *(const float4*)rp; p1 = *(const float4*)(rp + 4); }
        float t[8] = {p0.x,p0.y,p0.z,p0.w,p1.x,p1.y,p1.z,p1.w};
        s8v ah, al;
        #pragma unroll
        for (int j = 0; j < 8; j++) {
            unsigned short hb = f2bf(t[j]);
            ah[j] = (short)hb;
            al[j] = (short)f2bf(t[j] - bf2f(hb));
        }
        s8v bh[4], bl[4];
        #pragma unroll
        for (int ntl = 0; ntl < 4; ntl++) {
            size_t o = ((size_t)(ks * 16 + nt0 + ntl) * 64 + lane) * 8;  // fragment-major, NTILE=16
            bh[ntl] = *(const s8v*)(wth + o);
            bl[ntl] = *(const s8v*)(wtl + o);
        }
        #pragma unroll
        for (int ntl = 0; ntl < 4; ntl++) acch[ntl] = mfma16(ah, bh[ntl], acch[ntl]);
        #pragma unroll
        for (int ntl = 0; ntl < 4; ntl++) accl[ntl] = mfma16(al, bh[ntl], accl[ntl]);
        #pragma unroll
        for (int ntl = 0; ntl < 4; ntl++) accl[ntl] = mfma16(ah, bl[ntl], accl[ntl]);
    }

    // stage SC tile (rows local 0..15, cols 0..255) in LDS
    #pragma unroll
    for (int ntl = 0; ntl < 4; ntl++) {
        int col = (nt0 + ntl) * 16 + rm;
        float bb = b1[col];
        #pragma unroll
        for (int r = 0; r < 4; r++) {
            int lr = g * 4 + r;
            SC[lr * 260 + col] = acch[ntl][r] + accl[ntl][r] + bb;
        }
    }
    __syncthreads();

    // LN -> relu -> W2 per row (wave wv handles rows wv*4 .. wv*4+3)
    #pragma unroll
    for (int rr = 0; rr < 4; rr++) {
        int lr = wv * 4 + rr;
        int orow = rbase + lr;
        const float* sp = SC + lr * 260;
        float v0 = sp[lane], v1 = sp[lane + 64], v2 = sp[lane + 128], v3 = sp[lane + 192];
        float s = wredf(v0 + v1 + v2 + v3);
        float q = wredf(v0 * v0 + v1 * v1 + v2 * v2 + v3 * v3);
        float m = s * (1.f / 256.f);
        float var = q * (1.f / 256.f) - m * m;
        float rs = rsqrtf(var + 1e-5f);
        float h0 = fmaxf((v0 - m) * rs * lng[lane]       + lnb[lane],       0.f);
        float h1 = fmaxf((v1 - m) * rs * lng[lane + 64]  + lnb[lane + 64],  0.f);
        float h2 = fmaxf((v2 - m) * rs * lng[lane + 128] + lnb[lane + 128], 0.f);
        float h3 = fmaxf((v3 - m) * rs * lng[lane + 192] + lnb[lane + 192], 0.f);
        float p0 = h0 * W2[lane * 2]             + h1 * W2[(lane + 64) * 2]
                 + h2 * W2[(lane + 128) * 2]     + h3 * W2[(lane + 192) * 2];
        float p1 = h0 * W2[lane * 2 + 1]         + h1 * W2[(lane + 64) * 2 + 1]
                 + h2 * W2[(lane + 128) * 2 + 1] + h3 * W2[(lane + 192) * 2 + 1];
        p0 = wredf(p0);
        p1 = wredf(p1);
        if (lane == 0 && orow < M) {
            out[(size_t)orow * 2]     = p0 + b2[0];
            out[(size_t)orow * 2 + 1] = p1 + b2[1];
        }
    }
}

// ================================================================ host
extern "C" void kernel_launch(void* const* d_in, const int* in_sizes, int n_in,
                              void* d_out, int out_size, void* d_ws, size_t ws_size,
                              hipStream_t stream) {
    const float* x    = (const float*)d_in[0];
    const int*   srcN = (const int*)d_in[1];
    const int*   dstE = (const int*)d_in[2];
    const float* norm = (const float*)d_in[3];
    const float* elng = (const float*)d_in[4];
    const float* elnb = (const float*)d_in[5];
    const float* eW   = (const float*)d_in[6];
    const float* eB   = (const float*)d_in[7];
    const float* dW   = (const float*)d_in[8];
    const float* dB   = (const float*)d_in[9];
    const float* W1   = (const float*)d_in[10];
    const float* b1   = (const float*)d_in[11];
    const float* clng = (const float*)d_in[12];
    const float* clnb = (const float*)d_in[13];
    const float* W2   = (const float*)d_in[14];
    const float* b2   = (const float*)d_in[15];

    const int N = in_sizes[0] / 128;
    const int E = in_sizes[1];
    const int M = (out_size - N * 128) / 130;
    const int nbD = (M + 255) >> 8;
    const int nbS = (N + 255) >> 8;

    // workspace carve
    char* p = (char*)d_ws;
    auto carve = [&](size_t bytes) { void* q = (void*)p; p += ((bytes + 255) / 256) * 256; return q; };
    int*   minv  = (int*)carve(4);
    int*   bcD   = (int*)carve((size_t)nbD * 4);
    int*   bcS   = (int*)carve((size_t)nbS * 4);
    int*   bbD   = (int*)carve((size_t)(nbD + 1) * 4);
    int*   bbS   = (int*)carve((size_t)(nbS + 1) * 4);
    int*   curD  = (int*)carve((size_t)nbD * 4);
    int*   curS  = (int*)carve((size_t)nbS * 4);
    int*   rpM   = (int*)carve((size_t)(M + 1) * 4);
    int*   rpN   = (int*)carve((size_t)(N + 1) * 4);
    int2*  pairD = (int2*)carve((size_t)E * 8);
    int2*  pairS = (int2*)carve((size_t)E * 8);
    float* stats = (float*)carve(16 * 132 * 4);
    unsigned short* encTh = (unsigned short*)carve((size_t)5 * 16384 * 2);
    unsigned short* encTl = (unsigned short*)carve((size_t)5 * 16384 * 2);
    unsigned short* decTh = (unsigned short*)carve((size_t)5 * 16384 * 2);
    unsigned short* decTl = (unsigned short*)carve((size_t)5 * 16384 * 2);
    unsigned short* w1Th  = (unsigned short*)carve((size_t)384 * 256 * 2);
    unsigned short* w1Tl  = (unsigned short*)carve((size_t)384 * 256 * 2);
    float* hbuf  = (float*)carve((size_t)N * 128 * 4);            // dec fp32 out; hb16 overlay
    unsigned short* aggh = (unsigned short*)carve((size_t)N * 128 * 2);  // agg hi plane
    unsigned short* aggl = (unsigned short*)carve((size_t)N * 128 * 2);  // agg lo plane; aln16 overlay (disjoint windows)
    float* e0    = (float*)carve((size_t)M * 128 * 4);
    float* e1    = (float*)carve((size_t)M * 128 * 4);
    unsigned short* hb16  = (unsigned short*)hbuf;     // enc bf16 out; dead before dec writes hbuf
    unsigned short* aln16 = aggl;                      // LN'd bf16 A; live only while aggl dead
    int2*  tmpD = (int2*)e0;                           // bucket-grouped entries (graph build only)
    int2*  tmpS = (int2*)e1;

    float* outf      = (float*)d_out;
    float* score     = outf;                                   // [M,2]
    float* edge_feat = outf + (size_t)M * 2;                   // [M,128]
    float* node_feat = outf + (size_t)M * 2 + (size_t)M * 128; // [N,128]

    // ---- weight prep (transpose + split-bf16, fragment-major)
    k_prepT<<<320, 256, 0, stream>>>(eW, 5, 128, 128, encTh, encTl);
    k_prepT<<<320, 256, 0, stream>>>(dW, 5, 128, 128, decTh, decTl);
    k_prepT<<<384, 256, 0, stream>>>(W1, 1, 384, 256, w1Th, w1Tl);

    // ---- graph structure: bucket count -> bucket scan -> partition -> per-bucket rowptr+CSR place
    hipMemsetAsync(minv, 0x7f, 4, stream);
    hipMemsetAsync(bcD, 0, (size_t)nbD * 4, stream);
    hipMemsetAsync(bcS, 0, (size_t)nbS * 4, stream);
    k_min<<<256, 256, 0, stream>>>(dstE, E, minv);
    k_bcount<<<(E + BC_CHUNK - 1) / BC_CHUNK, 256, 0, stream>>>(dstE, srcN, minv, E, nbD, nbS, bcD, bcS);
    k_scan<<<1, 1024, 0, stream>>>(bcD, nbD, bbD);
    k_scan<<<1, 1024, 0, stream>>>(bcS, nbS, bbS);
    k_curinit<<<(max(nbD, nbS) + 255) / 256, 256, 0, stream>>>(bbD, bbS, nbD, nbS, curD, curS);
    k_part<<<(E + PART_CHUNK - 1) / PART_CHUNK, 256, 0, stream>>>(
        dstE, srcN, norm, minv, E, nbD, nbS, curD, curS, tmpD, tmpS);
    k_place<<<nbD, 256, 0, stream>>>(tmpD, bbD, M, nbD, pairD, rpM);
    k_place<<<nbS, 256, 0, stream>>>(tmpS, bbS, N, nbS, pairS, rpN);

    // ---- matmul dispatch helpers
    auto mmenc = [&](int rows, int k) {
        if (rows > 30000)
            k_mm16<0,0><<<(rows + 31) / 32, 256, 0, stream>>>(
                aln16, nullptr, rows, encTh + (size_t)k * 16384, encTl + (size_t)k * 16384,
                eB + (size_t)k * 128, hb16, nullptr);
        else
            k_mm16<1,0><<<(rows + 15) / 16, 256, 0, stream>>>(
                aln16, nullptr, rows, encTh + (size_t)k * 16384, encTl + (size_t)k * 16384,
                eB + (size_t)k * 128, hb16, nullptr);
    };
    auto mmdec = [&](int rows, int k) {
        if (rows > 30000)
            k_mm16<0,1><<<(rows + 31) / 32, 256, 0, stream>>>(
                aggh, aggl, rows, decTh + (size_t)k * 16384, decTl + (size_t)k * 16384,
                dB + (size_t)k * 128, hbuf, stats);
        else
            k_mm16<1,1><<<(rows + 15) / 16, 256, 0, stream>>>(
                aggh, aggl, rows, decTh + (size_t)k * 16384, decTl + (size_t)k * 16384,
                dB + (size_t)k * 128, hbuf, stats);
    };

    // ---- one half-conv: enc(bf16 A) -> CSR-mean agg (split hi/lo) -> dec(fused stats) -> rowprep tail
    auto conv = [&](int S, int T, int k, int v2e, float* dest) {
        mmenc(S, k);
        if (v2e)
            k_aggregate<<<(T + 15) / 16, 256, 0, stream>>>(hb16, rpM, pairD, aggh, aggl, T);
        else
            k_aggregate<<<(T + 15) / 16, 256, 0, stream>>>(hb16, rpN, pairS, aggh, aggl, T);
        hipMemsetAsync(stats, 0, 16 * 132 * 4, stream);
        mmdec(T, k);
        k_finalize<<<1, 128, 0, stream>>>(stats, T);
        if (k < 4) {
            // fused: center_scale -> dest (skipped if dead), then preop+LN+bf16 for conv k+1's enc A
            k_rowprep<<<(T + 15) / 16, 256, 0, stream>>>(
                hbuf, T, stats, dest, 1,
                elng + (size_t)(k + 1) * 128, elnb + (size_t)(k + 1) * 128, aln16);
        } else {
            size_t tot4 = ((size_t)T * 128) / 4;
            k_apply<<<(unsigned)((tot4 + 255) / 256), 256, 0, stream>>>(hbuf, stats, dest, T);
        }
    };

    // conv0's enc A from raw x (no preop, LN params k=0)
    k_rowprep<<<(N + 15) / 16, 256, 0, stream>>>(x, N, nullptr, nullptr, 0, elng, elnb, aln16);
    conv(N, M, 0, 1, e0);         // V2E0  (tail preps conv1's A at M rows)
    conv(M, N, 1, 0, nullptr);    // E2V0  (nf1 is dead — overwritten by conv3 before any read)
    conv(N, M, 2, 1, e1);         // V2E1
    conv(M, N, 3, 0, node_feat);  // E2V1 -> final node_feat
    conv(N, M, 4, 1, edge_feat);  // V2E2 -> final edge_feat (plain apply tail)

    k_cls<<<(M + 15) / 16, 256, 0, stream>>>(
        e0, e1, edge_feat, w1Th, w1Tl, b1, clng, clnb, W2, b2, score, M);
}

// Round 17
// 602.801 us; speedup vs baseline: 1.0587x; 1.0412x over previous
//
#include <hip/hip_runtime.h>
#include <math.h>

#define BNS 0.9999950000374997f  /* 1/sqrt(1+1e-5) */

typedef short s8v __attribute__((ext_vector_type(8)));
typedef float f4v __attribute__((ext_vector_type(4)));

// fragment-major A offset for element block: row tile t, k-slice ks, lane = g*16+rm
static __device__ __forceinline__ size_t a_frag_off(int row, int l16) {
    // producer view: quarter-wave lane l16 owns cols [l16*8, l16*8+8) of `row`
    return ((size_t)(row >> 4) * 4 + (l16 >> 2)) * 512 + (size_t)(((l16 & 3) << 4) + (row & 15)) * 8;
}

// ---------------------------------------------------------------- utilities
static __device__ __forceinline__ float wredf(float v) {
    #pragma unroll
    for (int o = 32; o; o >>= 1) v += __shfl_xor(v, o);
    return v;
}

static __device__ __forceinline__ unsigned short f2bf(float f) {
    unsigned int u = __float_as_uint(f);
    u = (u + 0x7fffu + ((u >> 16) & 1u)) >> 16;  // RNE
    return (unsigned short)u;
}

static __device__ __forceinline__ float bf2f(unsigned short b) {
    return __uint_as_float((unsigned int)b << 16);
}

static __device__ __forceinline__ f4v mfma16(s8v a, s8v b, f4v c) {
    return __builtin_amdgcn_mfma_f32_16x16x32_bf16(a, b, c, 0, 0, 0);
}

// ---------------------------------------------------------------- min of dst
__global__ void k_min(const int* __restrict__ d, int E, int* __restrict__ mn) {
    int i = blockIdx.x * blockDim.x + threadIdx.x;
    int v = 0x7FFFFFFF;
    for (; i < E; i += gridDim.x * blockDim.x) v = min(v, d[i]);
    #pragma unroll
    for (int o = 32; o; o >>= 1) v = min(v, __shfl_xor(v, o));
    if ((threadIdx.x & 63) == 0) atomicMin(mn, v);
}

// ---------------------------------------------------------------- bucket histogram (256-row buckets; LDS-aggregated)
#define BC_CHUNK 4096
__global__ __launch_bounds__(256) void k_bcount(
        const int* __restrict__ dst, const int* __restrict__ src,
        const int* __restrict__ minbuf, int E, int nbD, int nbS,
        int* __restrict__ bcD, int* __restrict__ bcS) {
    __shared__ int hD[128];
    __shared__ int hS[512];
    int tid = threadIdx.x;
    int mn = minbuf[0];
    int base = blockIdx.x * BC_CHUNK;
    int limit = min(base + BC_CHUNK, E);
    for (int i = tid; i < nbD; i += 256) hD[i] = 0;
    for (int i = tid; i < nbS; i += 256) hS[i] = 0;
    __syncthreads();
    for (int e = base + tid; e < limit; e += 256) {
        atomicAdd(&hD[(dst[e] - mn) >> 8], 1);
        atomicAdd(&hS[src[e] >> 8], 1);
    }
    __syncthreads();
    for (int i = tid; i < nbD; i += 256) { int c = hD[i]; if (c) atomicAdd(&bcD[i], c); }
    for (int i = tid; i < nbS; i += 256) { int c = hS[i]; if (c) atomicAdd(&bcS[i], c); }
}

// ---------------------------------------------------------------- small scan (single block; bucket counts <=1024)
__global__ __launch_bounds__(1024) void k_scan(const int* __restrict__ cnt, int n,
                                               int* __restrict__ rowptr) {
    __shared__ int wsum[16];
    __shared__ int carry;
    int tid = threadIdx.x, lane = tid & 63, wv = tid >> 6;
    if (tid == 0) carry = 0;
    __syncthreads();
    for (int base = 0; base < n; base += 1024) {
        int i = base + tid;
        int v = (i < n) ? cnt[i] : 0;
        int x = v;
        #pragma unroll
        for (int o = 1; o < 64; o <<= 1) { int t = __shfl_up(x, o); if (lane >= o) x += t; }
        if (lane == 63) wsum[wv] = x;
        __syncthreads();
        if (tid < 16) {
            int s = wsum[tid];
            #pragma unroll
            for (int o = 1; o < 16; o <<= 1) { int t = __shfl_up(s, o); if (tid >= o) s += t; }
            wsum[tid] = s;
        }
        __syncthreads();
        int woff = (wv == 0) ? 0 : wsum[wv - 1];
        int excl = carry + woff + x - v;
        if (i < n) rowptr[i] = excl;
        __syncthreads();
        if (tid == 1023) carry = carry + wsum[15];
        __syncthreads();
    }
    if (tid == 0) rowptr[n] = carry;
}

// ---------------------------------------------------------------- bucket cursor init: cur = copy of bucket bases
__global__ void k_curinit(const int* __restrict__ bbD, const int* __restrict__ bbS,
                          int nbD, int nbS,
                          int* __restrict__ curD, int* __restrict__ curS) {
    int i = blockIdx.x * blockDim.x + threadIdx.x;
    if (i < nbD) curD[i] = bbD[i];
    if (i < nbS) curS[i] = bbS[i];
}

// ---------------------------------------------------------------- phase A: bucket partition with run reservation
// Entries packed: .x = (local_row<<24) | gather_row (local<256, gather<2^24).
#define PART_CHUNK 4096
__global__ __launch_bounds__(256) void k_part(
        const int* __restrict__ dst, const int* __restrict__ src,
        const float* __restrict__ norm, const int* __restrict__ minbuf, int E,
        int nbD, int nbS, int* __restrict__ curD, int* __restrict__ curS,
        int2* __restrict__ tmpD, int2* __restrict__ tmpS) {
    __shared__ int histD[128];
    __shared__ int histS[512];
    int tid = threadIdx.x;
    int mn = minbuf[0];
    int base = blockIdx.x * PART_CHUNK;
    int limit = min(base + PART_CHUNK, E);
    for (int i = tid; i < nbD; i += 256) histD[i] = 0;
    for (int i = tid; i < nbS; i += 256) histS[i] = 0;
    __syncthreads();
    for (int e = base + tid; e < limit; e += 256) {
        int d = dst[e] - mn;
        int s = src[e];
        atomicAdd(&histD[d >> 8], 1);
        atomicAdd(&histS[s >> 8], 1);
    }
    __syncthreads();
    for (int i = tid; i < nbD; i += 256) {
        int c = histD[i];
        histD[i] = c ? atomicAdd(&curD[i], c) : 0;
    }
    for (int i = tid; i < nbS; i += 256) {
        int c = histS[i];
        histS[i] = c ? atomicAdd(&curS[i], c) : 0;
    }
    __syncthreads();
    for (int e = base + tid; e < limit; e += 256) {
        int d = dst[e] - mn;
        int s = src[e];
        int w = __float_as_int(norm[e]);
        int pD = atomicAdd(&histD[d >> 8], 1);
        tmpD[pD] = make_int2(((d & 255) << 24) | s, w);
        int pS = atomicAdd(&histS[s >> 8], 1);
        tmpS[pS] = make_int2(((s & 255) << 24) | d, w);
    }
}

// ---------------------------------------------------------------- phase B: per-bucket (256 rows) rowptr build + CSR placement
__global__ __launch_bounds__(256) void k_place(
        const int2* __restrict__ tmp, const int* __restrict__ bb, int nrows, int nbuckets,
        int2* __restrict__ pairs, int* __restrict__ rowptr) {
    int b = blockIdx.x;
    int r0 = b << 8;
    int tid = threadIdx.x, lane = tid & 63, wvi = tid >> 6;
    __shared__ int cnt[256];
    __shared__ int cur[256];
    __shared__ int ws[4];
    cnt[tid] = 0;
    __syncthreads();
    int beg = bb[b], end = bb[b + 1];
    for (int p = beg + tid; p < end; p += 256)
        atomicAdd(&cnt[((unsigned)tmp[p].x) >> 24], 1);
    __syncthreads();
    int c = cnt[tid];
    int x = c;
    #pragma unroll
    for (int o = 1; o < 64; o <<= 1) { int t = __shfl_up(x, o); if (lane >= o) x += t; }
    if (lane == 63) ws[wvi] = x;
    __syncthreads();
    int woff = 0;
    for (int i = 0; i < wvi; i++) woff += ws[i];
    int rpv = beg + woff + x - c;
    if (r0 + tid < nrows) rowptr[r0 + tid] = rpv;
    cur[tid] = rpv;
    if (b == 0 && tid == 0) rowptr[nrows] = bb[nbuckets];
    __syncthreads();
    for (int p = beg + tid; p < end; p += 256) {
        int2 en = tmp[p];
        int l = ((unsigned)en.x) >> 24;
        int pos = atomicAdd(&cur[l], 1);
        pairs[pos] = make_int2(en.x & 0xFFFFFF, en.y);
    }
}

// ---------------------------------------------------------------- weight prep: fp32 [K][Nn] -> FRAGMENT-MAJOR bf16 hi/lo
__global__ void k_prepT(const float* __restrict__ in, int nmat, int K, int Nn,
                        unsigned short* __restrict__ oh, unsigned short* __restrict__ ol) {
    int total = nmat * K * Nn;
    int ntile = Nn >> 4;
    for (int i = blockIdx.x * blockDim.x + threadIdx.x; i < total; i += gridDim.x * blockDim.x) {
        int m = i / (K * Nn), r = i % (K * Nn);
        int k = r / Nn, n = r % Nn;
        float v = in[i];
        unsigned short hb = f2bf(v);
        float lo = v - bf2f(hb);
        int ks = k >> 5, g = (k >> 3) & 3, j = k & 7;
        int nt = n >> 4, rm = n & 15;
        size_t o = (size_t)m * K * Nn + ((size_t)(ks * ntile + nt) * 64 + g * 16 + rm) * 8 + j;
        oh[o] = hb;
        ol[o] = f2bf(lo);
    }
}

// ---------------------------------------------------------------- row prep: center_scale -> dest fp32, then preop->LN->bf16 A (fragment-major)
// quarter-wave (16 lanes) per row; 16 rows/block.
__global__ __launch_bounds__(256) void k_rowprep(
        const float* __restrict__ in, int S,
        const float* __restrict__ stats,   // null: skip center_scale
        float* __restrict__ dest,          // null: skip fp32 output
        int preop,
        const float* __restrict__ lng, const float* __restrict__ lnb,
        unsigned short* __restrict__ aln) {
    int lane = threadIdx.x & 63, wv = threadIdx.x >> 6;
    int sub = lane >> 4, l16 = lane & 15;
    int row = blockIdx.x * 16 + wv * 4 + sub;
    if (row >= S) return;
    const float* rp = in + (size_t)row * 128 + l16 * 8;
    float4 p0 = *(const float4*)rp;
    float4 p1 = *(const float4*)(rp + 4);
    float v[8] = {p0.x,p0.y,p0.z,p0.w,p1.x,p1.y,p1.z,p1.w};
    if (stats) {
        float inv = stats[128];
        const float4 m0 = *(const float4*)(stats + l16 * 8);
        const float4 m1 = *(const float4*)(stats + l16 * 8 + 4);
        float mu[8] = {m0.x,m0.y,m0.z,m0.w,m1.x,m1.y,m1.z,m1.w};
        #pragma unroll
        for (int j = 0; j < 8; j++) v[j] = (v[j] - mu[j]) * inv;
        if (dest) {
            float* dp = dest + (size_t)row * 128 + l16 * 8;
            *(float4*)dp       = make_float4(v[0], v[1], v[2], v[3]);
            *(float4*)(dp + 4) = make_float4(v[4], v[5], v[6], v[7]);
        }
    }
    float s = 0.f, q = 0.f;
    #pragma unroll
    for (int j = 0; j < 8; j++) {
        float x = v[j];
        if (preop) x = fmaxf(x * BNS, 0.f);
        v[j] = x;
        s += x; q += x * x;
    }
    #pragma unroll
    for (int o = 1; o < 16; o <<= 1) { s += __shfl_xor(s, o); q += __shfl_xor(q, o); }
    float m = s * (1.f / 128.f);
    float var = q * (1.f / 128.f) - m * m;
    float rs = rsqrtf(var + 1e-5f);
    const float4 g0 = *(const float4*)(lng + l16 * 8);
    const float4 g1 = *(const float4*)(lng + l16 * 8 + 4);
    const float4 b0 = *(const float4*)(lnb + l16 * 8);
    const float4 b1 = *(const float4*)(lnb + l16 * 8 + 4);
    float gg[8] = {g0.x,g0.y,g0.z,g0.w,g1.x,g1.y,g1.z,g1.w};
    float bb[8] = {b0.x,b0.y,b0.z,b0.w,b1.x,b1.y,b1.z,b1.w};
    s8v o;
    #pragma unroll
    for (int j = 0; j < 8; j++)
        o[j] = (short)f2bf((v[j] - m) * rs * gg[j] + bb[j]);
    *(s8v*)(aln + a_frag_off(row, l16)) = o;
}

// ---------------------------------------------------------------- MFMA matmul, fragment-major A AND B
// NSPLIT=0: 32 rows/block, 2 m-waves x 2 n-waves, NT=4   (large S)
// NSPLIT=1: 16 rows/block, 4 n-waves, NT=2               (small S)
// DEC=0 (enc): A=hi only; bf16 row-major out.  DEC=1 (dec): A=hi+lo; fp32 out + banked stats.
template<int NSPLIT, int DEC>
__global__ __launch_bounds__(256, 6) void k_mm16(
        const unsigned short* __restrict__ ainh, const unsigned short* __restrict__ ainl,
        int S,
        const unsigned short* __restrict__ wth, const unsigned short* __restrict__ wtl,
        const float* __restrict__ bias, void* __restrict__ outv,
        float* __restrict__ stats) {
    int lane = threadIdx.x & 63, wv = threadIdx.x >> 6;
    int g = lane >> 4;          // k-group 0..3
    int rm = lane & 15;         // A-row within tile / C-col
    constexpr int NT = NSPLIT ? 2 : 4;
    int rbase, nt0;
    if (NSPLIT) { rbase = blockIdx.x * 16;                  nt0 = wv * 2; }
    else        { rbase = blockIdx.x * 32 + (wv >> 1) * 16; nt0 = (wv & 1) * 4; }

    // ---- A fragments: fully coalesced 1 KB wave loads (fragment-major; buffer tile-padded)
    s8v ah[4], al[4];
    {
        const unsigned short* ap = ainh + (size_t)(rbase >> 4) * 2048 + lane * 8;
        const unsigned short* lp = DEC ? (ainl + (size_t)(rbase >> 4) * 2048 + lane * 8) : ap;
        #pragma unroll
        for (int ks = 0; ks < 4; ks++) {
            ah[ks] = *(const s8v*)(ap + ks * 512);
            if (DEC) al[ks] = *(const s8v*)(lp + ks * 512);
        }
    }

    f4v acch[NT] = {};
    f4v accl[NT] = {};
    #pragma unroll
    for (int ks = 0; ks < 4; ks++) {
        s8v bh[NT], bl[NT];
        #pragma unroll
        for (int ntl = 0; ntl < NT; ntl++) {
            size_t o = ((size_t)(ks * 8 + nt0 + ntl) * 64 + lane) * 8;  // fragment-major, NTILE=8
            bh[ntl] = *(const s8v*)(wth + o);
            bl[ntl] = *(const s8v*)(wtl + o);
        }
        #pragma unroll
        for (int ntl = 0; ntl < NT; ntl++)
            acch[ntl] = mfma16(ah[ks], bh[ntl], acch[ntl]);
        #pragma unroll
        for (int ntl = 0; ntl < NT; ntl++)
            accl[ntl] = mfma16(ah[ks], bl[ntl], accl[ntl]);
        if (DEC) {
            #pragma unroll
            for (int ntl = 0; ntl < NT; ntl++)
                accl[ntl] = mfma16(al[ks], bh[ntl], accl[ntl]);
        }
    }

    __shared__ float cs[129];
    if (DEC && stats) {
        for (int i = threadIdx.x; i < 129; i += 256) cs[i] = 0.f;
        __syncthreads();
    }
    float myq = 0.f;
    #pragma unroll
    for (int ntl = 0; ntl < NT; ntl++) {
        int ntg = nt0 + ntl;
        float bb = bias[ntg * 16 + rm];
        float cp = 0.f;
        #pragma unroll
        for (int r = 0; r < 4; r++) {
            int orow = rbase + g * 4 + r;   // C row mapping
            float val = fmaxf(acch[ntl][r] + accl[ntl][r] + bb, 0.f);
            bool vok = orow < S;
            if (!DEC) {
                unsigned int bits = f2bf(val);
                unsigned int pb = (unsigned int)__shfl_xor((int)bits, 1);
                if (!(lane & 1) && vok) {
                    unsigned int word = bits | (pb << 16);
                    ((unsigned int*)outv)[((size_t)orow * 128 + ntg * 16 + rm) >> 1] = word;
                }
            } else {
                if (vok) ((float*)outv)[(size_t)orow * 128 + ntg * 16 + rm] = val;
                if (stats && vok) { cp += val; myq += val * val; }
            }
        }
        if (DEC && stats) {
            cp += __shfl_xor(cp, 16);
            cp += __shfl_xor(cp, 32);
            if (g == 0) atomicAdd(&cs[ntg * 16 + rm], cp);
        }
    }
    if (DEC && stats) {
        myq = wredf(myq);
        if (lane == 0) atomicAdd(&cs[128], myq);
        __syncthreads();
        float* sb = stats + (size_t)(blockIdx.x & 15) * 132;
        for (int i = threadIdx.x; i < 129; i += 256) {
            float v = cs[i];
            if (v != 0.f) atomicAdd(&sb[i], v);
        }
    }
}

// ---------------------------------------------------------------- CSR gather aggregation -> split hi/lo bf16, fragment-major out
// quarter-wave per row: 16 lanes x dwordx4 = 256 B row; 16 rows/block.
__global__ __launch_bounds__(256) void k_aggregate(
        const unsigned short* __restrict__ h, const int* __restrict__ rowptr,
        const int2* __restrict__ pairs,
        unsigned short* __restrict__ aggh, unsigned short* __restrict__ aggl, int T) {
    int lane = threadIdx.x & 63, wv = threadIdx.x >> 6;
    int sub = lane >> 4, l16 = lane & 15;
    int row = blockIdx.x * 16 + wv * 4 + sub;
    if (row >= T) return;
    int beg = rowptr[row], end = rowptr[row + 1];
    float a[8] = {0.f,0.f,0.f,0.f,0.f,0.f,0.f,0.f};
    #pragma unroll 4
    for (int p = beg; p < end; ++p) {
        int2 pr = pairs[p];
        const uint4 v = *(const uint4*)(h + (size_t)pr.x * 128 + l16 * 8);
        float w = __int_as_float(pr.y);
        a[0] = fmaf(w, __uint_as_float(v.x << 16),          a[0]);
        a[1] = fmaf(w, __uint_as_float(v.x & 0xffff0000u),  a[1]);
        a[2] = fmaf(w, __uint_as_float(v.y << 16),          a[2]);
        a[3] = fmaf(w, __uint_as_float(v.y & 0xffff0000u),  a[3]);
        a[4] = fmaf(w, __uint_as_float(v.z << 16),          a[4]);
        a[5] = fmaf(w, __uint_as_float(v.z & 0xffff0000u),  a[5]);
        a[6] = fmaf(w, __uint_as_float(v.w << 16),          a[6]);
        a[7] = fmaf(w, __uint_as_float(v.w & 0xffff0000u),  a[7]);
    }
    float invc = 1.f / fmaxf((float)(end - beg), 1.f);
    s8v oh, ol;
    #pragma unroll
    for (int j = 0; j < 8; j++) {
        float v = a[j] * invc;
        unsigned short hb = f2bf(v);
        oh[j] = (short)hb;
        ol[j] = (short)f2bf(v - bf2f(hb));
    }
    size_t fo = a_frag_off(row, l16);
    *(s8v*)(aggh + fo) = oh;
    *(s8v*)(aggl + fo) = ol;
}

// ---------------------------------------------------------------- finalize banked center_scale stats: mu[c], inv at [128]
__global__ void k_finalize(float* __restrict__ stats, int n) {
    int c = threadIdx.x;  // 128 threads
    float su = 0.f;
    #pragma unroll
    for (int b = 0; b < 16; b++) su += stats[b * 132 + c];
    float mu = su / (float)n;
    stats[c] = mu;
    float m2 = mu * mu;
    #pragma unroll
    for (int o = 32; o; o >>= 1) m2 += __shfl_xor(m2, o);
    __shared__ float ws2[2];
    if ((c & 63) == 0) ws2[c >> 6] = m2;
    __syncthreads();
    if (c == 0) {
        float qs = 0.f;
        #pragma unroll
        for (int b = 0; b < 16; b++) qs += stats[b * 132 + 128];
        float musq = ws2[0] + ws2[1];
        float msn = qs / (float)n - musq;  // mean ||x_i - mu||^2
        stats[128] = rsqrtf(1e-5f + msn);
    }
}

// ---------------------------------------------------------------- apply center_scale (conv4 tail only)
__global__ void k_apply(const float* __restrict__ in, const float* __restrict__ stats,
                        float* __restrict__ out, int n) {
    size_t i = ((size_t)blockIdx.x * blockDim.x + threadIdx.x) * 4;
    size_t tot = (size_t)n * 128;
    if (i >= tot) return;
    float inv = stats[128];
    int c = (int)(i & 127);
    float4 v = *(const float4*)(in + i);
    v.x = (v.x - stats[c])     * inv;
    v.y = (v.y - stats[c + 1]) * inv;
    v.z = (v.z - stats[c + 2]) * inv;
    v.w = (v.w - stats[c + 3]) * inv;
    *(float4*)(out + i) = v;
}

// ---------------------------------------------------------------- fused classifier: [M,384]@[384,256]+b1 -> LN -> relu -> @[256,2]+b2
__global__ __launch_bounds__(256) void k_cls(
        const float* __restrict__ e0, const float* __restrict__ e1, const float* __restrict__ e2,
        const unsigned short* __restrict__ wth, const unsigned short* __restrict__ wtl,
        const float* __restrict__ b1,
        const float* __restrict__ lng, const float* __restrict__ lnb,
        const float* __restrict__ W2, const float* __restrict__ b2,
        float* __restrict__ out, int M) {
    __shared__ float SC[16 * 260];
    int lane = threadIdx.x & 63, wv = threadIdx.x >> 6;
    int g = lane >> 4, rm = lane & 15;
    int rbase = blockIdx.x * 16;
    int nt0 = wv * 4;
    int row = rbase + rm;
    bool ok = row < M;

    f4v acch[4] = {};
    f4v accl[4] = {};
    #pragma unroll
    for (int ks = 0; ks < 12; ks++) {
        const float* src = (ks < 4) ? e0 : (ks < 8) ? e1 : e2;
        const float* rp = src + (size_t)row * 128 + (ks & 3) * 32 + g * 8;
        float4 p0 = make_float4(0.f,0.f,0.f,0.f), p1 = make_float4(0.f,0.f,0.f,0.f);
        if (ok) { p0 = *(const float4*)rp; p1 = *(const float4*)(rp + 4); }
        float t[8] = {p0.x,p0.y,p0.z,p0.w,p1.x,p1.y,p1.z,p1.w};
        s8v ah, al;
        #pragma unroll
        for (int j = 0; j < 8; j++) {
            unsigned short hb = f2bf(t[j]);
            ah[j] = (short)hb;
            al[j] = (short)f2bf(t[j] - bf2f(hb));
        }
        s8v bh[4], bl[4];
        #pragma unroll
        for (int ntl = 0; ntl < 4; ntl++) {
            size_t o = ((size_t)(ks * 16 + nt0 + ntl) * 64 + lane) * 8;  // fragment-major, NTILE=16
            bh[ntl] = *(const s8v*)(wth + o);
            bl[ntl] = *(const s8v*)(wtl + o);
        }
        #pragma unroll
        for (int ntl = 0; ntl < 4; ntl++) acch[ntl] = mfma16(ah, bh[ntl], acch[ntl]);
        #pragma unroll
        for (int ntl = 0; ntl < 4; ntl++) accl[ntl] = mfma16(al, bh[ntl], accl[ntl]);
        #pragma unroll
        for (int ntl = 0; ntl < 4; ntl++) accl[ntl] = mfma16(ah, bl[ntl], accl[ntl]);
    }

    #pragma unroll
    for (int ntl = 0; ntl < 4; ntl++) {
        int col = (nt0 + ntl) * 16 + rm;
        float bb = b1[col];
        #pragma unroll
        for (int r = 0; r < 4; r++) {
            int lr = g * 4 + r;
            SC[lr * 260 + col] = acch[ntl][r] + accl[ntl][r] + bb;
        }
    }
    __syncthreads();

    #pragma unroll
    for (int rr = 0; rr < 4; rr++) {
        int lr = wv * 4 + rr;
        int orow = rbase + lr;
        const float* sp = SC + lr * 260;
        float v0 = sp[lane], v1 = sp[lane + 64], v2 = sp[lane + 128], v3 = sp[lane + 192];
        float s = wredf(v0 + v1 + v2 + v3);
        float q = wredf(v0 * v0 + v1 * v1 + v2 * v2 + v3 * v3);
        float m = s * (1.f / 256.f);
        float var = q * (1.f / 256.f) - m * m;
        float rs = rsqrtf(var + 1e-5f);
        float h0 = fmaxf((v0 - m) * rs * lng[lane]       + lnb[lane],       0.f);
        float h1 = fmaxf((v1 - m) * rs * lng[lane + 64]  + lnb[lane + 64],  0.f);
        float h2 = fmaxf((v2 - m) * rs * lng[lane + 128] + lnb[lane + 128], 0.f);
        float h3 = fmaxf((v3 - m) * rs * lng[lane + 192] + lnb[lane + 192], 0.f);
        float p0 = h0 * W2[lane * 2]             + h1 * W2[(lane + 64) * 2]
                 + h2 * W2[(lane + 128) * 2]     + h3 * W2[(lane + 192) * 2];
        float p1 = h0 * W2[lane * 2 + 1]         + h1 * W2[(lane + 64) * 2 + 1]
                 + h2 * W2[(lane + 128) * 2 + 1] + h3 * W2[(lane + 192) * 2 + 1];
        p0 = wredf(p0);
        p1 = wredf(p1);
        if (lane == 0 && orow < M) {
            out[(size_t)orow * 2]     = p0 + b2[0];
            out[(size_t)orow * 2 + 1] = p1 + b2[1];
        }
    }
}

// ================================================================ host
extern "C" void kernel_launch(void* const* d_in, const int* in_sizes, int n_in,
                              void* d_out, int out_size, void* d_ws, size_t ws_size,
                              hipStream_t stream) {
    const float* x    = (const float*)d_in[0];
    const int*   srcN = (const int*)d_in[1];
    const int*   dstE = (const int*)d_in[2];
    const float* norm = (const float*)d_in[3];
    const float* elng = (const float*)d_in[4];
    const float* elnb = (const float*)d_in[5];
    const float* eW   = (const float*)d_in[6];
    const float* eB   = (const float*)d_in[7];
    const float* dW   = (const float*)d_in[8];
    const float* dB   = (const float*)d_in[9];
    const float* W1   = (const float*)d_in[10];
    const float* b1   = (const float*)d_in[11];
    const float* clng = (const float*)d_in[12];
    const float* clnb = (const float*)d_in[13];
    const float* W2   = (const float*)d_in[14];
    const float* b2   = (const float*)d_in[15];

    const int N = in_sizes[0] / 128;
    const int E = in_sizes[1];
    const int M = (out_size - N * 128) / 130;
    const int nbD = (M + 255) >> 8;
    const int nbS = (N + 255) >> 8;

    // workspace carve
    char* p = (char*)d_ws;
    auto carve = [&](size_t bytes) { void* q = (void*)p; p += ((bytes + 255) / 256) * 256; return q; };
    int*   minv  = (int*)carve(4);
    int*   bcD   = (int*)carve((size_t)nbD * 4);
    int*   bcS   = (int*)carve((size_t)nbS * 4);
    int*   bbD   = (int*)carve((size_t)(nbD + 1) * 4);
    int*   bbS   = (int*)carve((size_t)(nbS + 1) * 4);
    int*   curD  = (int*)carve((size_t)nbD * 4);
    int*   curS  = (int*)carve((size_t)nbS * 4);
    int*   rpM   = (int*)carve((size_t)(M + 1) * 4);
    int*   rpN   = (int*)carve((size_t)(N + 1) * 4);
    int2*  pairD = (int2*)carve((size_t)E * 8);
    int2*  pairS = (int2*)carve((size_t)E * 8);
    float* stats = (float*)carve(16 * 132 * 4);
    unsigned short* encTh = (unsigned short*)carve((size_t)5 * 16384 * 2);
    unsigned short* encTl = (unsigned short*)carve((size_t)5 * 16384 * 2);
    unsigned short* decTh = (unsigned short*)carve((size_t)5 * 16384 * 2);
    unsigned short* decTl = (unsigned short*)carve((size_t)5 * 16384 * 2);
    unsigned short* w1Th  = (unsigned short*)carve((size_t)384 * 256 * 2);
    unsigned short* w1Tl  = (unsigned short*)carve((size_t)384 * 256 * 2);
    float* hbuf  = (float*)carve((size_t)N * 128 * 4 + 16384);           // dec fp32 out; hb16 overlay
    unsigned short* aggh = (unsigned short*)carve((size_t)N * 128 * 2 + 8192);  // agg hi plane (fragment-major, tile-padded)
    unsigned short* aggl = (unsigned short*)carve((size_t)N * 128 * 2 + 8192);  // agg lo plane; aln16 overlay
    float* e0    = (float*)carve((size_t)M * 128 * 4);
    float* e1    = (float*)carve((size_t)M * 128 * 4);
    unsigned short* hb16  = (unsigned short*)hbuf;     // enc bf16 out (row-major); dead before dec writes hbuf
    unsigned short* aln16 = aggl;                      // LN'd bf16 A (fragment-major); live only while aggl dead
    int2*  tmpD = (int2*)e0;                           // bucket-grouped entries (graph build only)
    int2*  tmpS = (int2*)e1;

    float* outf      = (float*)d_out;
    float* score     = outf;                                   // [M,2]
    float* edge_feat = outf + (size_t)M * 2;                   // [M,128]
    float* node_feat = outf + (size_t)M * 2 + (size_t)M * 128; // [N,128]

    // ---- weight prep (transpose + split-bf16, fragment-major)
    k_prepT<<<320, 256, 0, stream>>>(eW, 5, 128, 128, encTh, encTl);
    k_prepT<<<320, 256, 0, stream>>>(dW, 5, 128, 128, decTh, decTl);
    k_prepT<<<384, 256, 0, stream>>>(W1, 1, 384, 256, w1Th, w1Tl);

    // ---- graph structure: bucket count -> bucket scan -> partition -> per-bucket rowptr+CSR place
    hipMemsetAsync(minv, 0x7f, 4, stream);
    hipMemsetAsync(bcD, 0, (size_t)nbD * 4, stream);
    hipMemsetAsync(bcS, 0, (size_t)nbS * 4, stream);
    k_min<<<256, 256, 0, stream>>>(dstE, E, minv);
    k_bcount<<<(E + BC_CHUNK - 1) / BC_CHUNK, 256, 0, stream>>>(dstE, srcN, minv, E, nbD, nbS, bcD, bcS);
    k_scan<<<1, 1024, 0, stream>>>(bcD, nbD, bbD);
    k_scan<<<1, 1024, 0, stream>>>(bcS, nbS, bbS);
    k_curinit<<<(max(nbD, nbS) + 255) / 256, 256, 0, stream>>>(bbD, bbS, nbD, nbS, curD, curS);
    k_part<<<(E + PART_CHUNK - 1) / PART_CHUNK, 256, 0, stream>>>(
        dstE, srcN, norm, minv, E, nbD, nbS, curD, curS, tmpD, tmpS);
    k_place<<<nbD, 256, 0, stream>>>(tmpD, bbD, M, nbD, pairD, rpM);
    k_place<<<nbS, 256, 0, stream>>>(tmpS, bbS, N, nbS, pairS, rpN);

    // ---- matmul dispatch helpers
    auto mmenc = [&](int rows, int k) {
        if (rows > 30000)
            k_mm16<0,0><<<(rows + 31) / 32, 256, 0, stream>>>(
                aln16, nullptr, rows, encTh + (size_t)k * 16384, encTl + (size_t)k * 16384,
                eB + (size_t)k * 128, hb16, nullptr);
        else
            k_mm16<1,0><<<(rows + 15) / 16, 256, 0, stream>>>(
                aln16, nullptr, rows, encTh + (size_t)k * 16384, encTl + (size_t)k * 16384,
                eB + (size_t)k * 128, hb16, nullptr);
    };
    auto mmdec = [&](int rows, int k) {
        if (rows > 30000)
            k_mm16<0,1><<<(rows + 31) / 32, 256, 0, stream>>>(
                aggh, aggl, rows, decTh + (size_t)k * 16384, decTl + (size_t)k * 16384,
                dB + (size_t)k * 128, hbuf, stats);
        else
            k_mm16<1,1><<<(rows + 15) / 16, 256, 0, stream>>>(
                aggh, aggl, rows, decTh + (size_t)k * 16384, decTl + (size_t)k * 16384,
                dB + (size_t)k * 128, hbuf, stats);
    };

    // ---- one half-conv: enc(bf16 A) -> CSR-mean agg (split hi/lo) -> dec(fused stats) -> rowprep tail
    auto conv = [&](int S, int T, int k, int v2e, float* dest) {
        mmenc(S, k);
        if (v2e)
            k_aggregate<<<(T + 15) / 16, 256, 0, stream>>>(hb16, rpM, pairD, aggh, aggl, T);
        else
            k_aggregate<<<(T + 15) / 16, 256, 0, stream>>>(hb16, rpN, pairS, aggh, aggl, T);
        hipMemsetAsync(stats, 0, 16 * 132 * 4, stream);
        mmdec(T, k);
        k_finalize<<<1, 128, 0, stream>>>(stats, T);
        if (k < 4) {
            // fused: center_scale -> dest (skipped if dead), then preop+LN+bf16 for conv k+1's enc A
            k_rowprep<<<(T + 15) / 16, 256, 0, stream>>>(
                hbuf, T, stats, dest, 1,
                elng + (size_t)(k + 1) * 128, elnb + (size_t)(k + 1) * 128, aln16);
        } else {
            size_t tot4 = ((size_t)T * 128) / 4;
            k_apply<<<(unsigned)((tot4 + 255) / 256), 256, 0, stream>>>(hbuf, stats, dest, T);
        }
    };

    // conv0's enc A from raw x (no preop, LN params k=0)
    k_rowprep<<<(N + 15) / 16, 256, 0, stream>>>(x, N, nullptr, nullptr, 0, elng, elnb, aln16);
    conv(N, M, 0, 1, e0);         // V2E0  (tail preps conv1's A at M rows)
    conv(M, N, 1, 0, nullptr);    // E2V0  (nf1 is dead — overwritten by conv3 before any read)
    conv(N, M, 2, 1, e1);         // V2E1
    conv(M, N, 3, 0, node_feat);  // E2V1 -> final node_feat
    conv(N, M, 4, 1, edge_feat);  // V2E2 -> final edge_feat (plain apply tail)

    k_cls<<<(M + 15) / 16, 256, 0, stream>>>(
        e0, e1, edge_feat, w1Th, w1Tl, b1, clng, clnb, W2, b2, score, M);
}

// Round 18
// 591.577 us; speedup vs baseline: 1.0788x; 1.0190x over previous
//
#include <hip/hip_runtime.h>
#include <math.h>

#define BNS 0.9999950000374997f  /* 1/sqrt(1+1e-5) */

typedef short s8v __attribute__((ext_vector_type(8)));
typedef float f4v __attribute__((ext_vector_type(4)));

// fragment-major A offset: quarter-wave lane l16 owns cols [l16*8, l16*8+8) of `row`
static __device__ __forceinline__ size_t a_frag_off(int row, int l16) {
    return ((size_t)(row >> 4) * 4 + (l16 >> 2)) * 512 + (size_t)(((l16 & 3) << 4) + (row & 15)) * 8;
}

// ---------------------------------------------------------------- utilities
static __device__ __forceinline__ float wredf(float v) {
    #pragma unroll
    for (int o = 32; o; o >>= 1) v += __shfl_xor(v, o);
    return v;
}

static __device__ __forceinline__ unsigned short f2bf(float f) {
    unsigned int u = __float_as_uint(f);
    u = (u + 0x7fffu + ((u >> 16) & 1u)) >> 16;  // RNE
    return (unsigned short)u;
}

static __device__ __forceinline__ float bf2f(unsigned short b) {
    return __uint_as_float((unsigned int)b << 16);
}

static __device__ __forceinline__ f4v mfma16(s8v a, s8v b, f4v c) {
    return __builtin_amdgcn_mfma_f32_16x16x32_bf16(a, b, c, 0, 0, 0);
}

// ---------------------------------------------------------------- min of dst
__global__ void k_min(const int* __restrict__ d, int E, int* __restrict__ mn) {
    int i = blockIdx.x * blockDim.x + threadIdx.x;
    int v = 0x7FFFFFFF;
    for (; i < E; i += gridDim.x * blockDim.x) v = min(v, d[i]);
    #pragma unroll
    for (int o = 32; o; o >>= 1) v = min(v, __shfl_xor(v, o));
    if ((threadIdx.x & 63) == 0) atomicMin(mn, v);
}

// ---------------------------------------------------------------- bucket histogram (256-row buckets; LDS-aggregated)
#define BC_CHUNK 4096
__global__ __launch_bounds__(256) void k_bcount(
        const int* __restrict__ dst, const int* __restrict__ src,
        const int* __restrict__ minbuf, int E, int nbD, int nbS,
        int* __restrict__ bcD, int* __restrict__ bcS) {
    __shared__ int hD[128];
    __shared__ int hS[512];
    int tid = threadIdx.x;
    int mn = minbuf[0];
    int base = blockIdx.x * BC_CHUNK;
    int limit = min(base + BC_CHUNK, E);
    for (int i = tid; i < nbD; i += 256) hD[i] = 0;
    for (int i = tid; i < nbS; i += 256) hS[i] = 0;
    __syncthreads();
    for (int e = base + tid; e < limit; e += 256) {
        atomicAdd(&hD[(dst[e] - mn) >> 8], 1);
        atomicAdd(&hS[src[e] >> 8], 1);
    }
    __syncthreads();
    for (int i = tid; i < nbD; i += 256) { int c = hD[i]; if (c) atomicAdd(&bcD[i], c); }
    for (int i = tid; i < nbS; i += 256) { int c = hS[i]; if (c) atomicAdd(&bcS[i], c); }
}

// ---------------------------------------------------------------- small scan (single block; bucket counts <=1024)
__global__ __launch_bounds__(1024) void k_scan(const int* __restrict__ cnt, int n,
                                               int* __restrict__ rowptr) {
    __shared__ int wsum[16];
    __shared__ int carry;
    int tid = threadIdx.x, lane = tid & 63, wv = tid >> 6;
    if (tid == 0) carry = 0;
    __syncthreads();
    for (int base = 0; base < n; base += 1024) {
        int i = base + tid;
        int v = (i < n) ? cnt[i] : 0;
        int x = v;
        #pragma unroll
        for (int o = 1; o < 64; o <<= 1) { int t = __shfl_up(x, o); if (lane >= o) x += t; }
        if (lane == 63) wsum[wv] = x;
        __syncthreads();
        if (tid < 16) {
            int s = wsum[tid];
            #pragma unroll
            for (int o = 1; o < 16; o <<= 1) { int t = __shfl_up(s, o); if (tid >= o) s += t; }
            wsum[tid] = s;
        }
        __syncthreads();
        int woff = (wv == 0) ? 0 : wsum[wv - 1];
        int excl = carry + woff + x - v;
        if (i < n) rowptr[i] = excl;
        __syncthreads();
        if (tid == 1023) carry = carry + wsum[15];
        __syncthreads();
    }
    if (tid == 0) rowptr[n] = carry;
}

// ---------------------------------------------------------------- bucket cursor init: cur = copy of bucket bases
__global__ void k_curinit(const int* __restrict__ bbD, const int* __restrict__ bbS,
                          int nbD, int nbS,
                          int* __restrict__ curD, int* __restrict__ curS) {
    int i = blockIdx.x * blockDim.x + threadIdx.x;
    if (i < nbD) curD[i] = bbD[i];
    if (i < nbS) curS[i] = bbS[i];
}

// ---------------------------------------------------------------- phase A: bucket partition with run reservation
// Entries packed: .x = (local_row<<24) | gather_row (local<256, gather<2^24).
#define PART_CHUNK 4096
__global__ __launch_bounds__(256) void k_part(
        const int* __restrict__ dst, const int* __restrict__ src,
        const float* __restrict__ norm, const int* __restrict__ minbuf, int E,
        int nbD, int nbS, int* __restrict__ curD, int* __restrict__ curS,
        int2* __restrict__ tmpD, int2* __restrict__ tmpS) {
    __shared__ int histD[128];
    __shared__ int histS[512];
    int tid = threadIdx.x;
    int mn = minbuf[0];
    int base = blockIdx.x * PART_CHUNK;
    int limit = min(base + PART_CHUNK, E);
    for (int i = tid; i < nbD; i += 256) histD[i] = 0;
    for (int i = tid; i < nbS; i += 256) histS[i] = 0;
    __syncthreads();
    for (int e = base + tid; e < limit; e += 256) {
        int d = dst[e] - mn;
        int s = src[e];
        atomicAdd(&histD[d >> 8], 1);
        atomicAdd(&histS[s >> 8], 1);
    }
    __syncthreads();
    for (int i = tid; i < nbD; i += 256) {
        int c = histD[i];
        histD[i] = c ? atomicAdd(&curD[i], c) : 0;
    }
    for (int i = tid; i < nbS; i += 256) {
        int c = histS[i];
        histS[i] = c ? atomicAdd(&curS[i], c) : 0;
    }
    __syncthreads();
    for (int e = base + tid; e < limit; e += 256) {
        int d = dst[e] - mn;
        int s = src[e];
        int w = __float_as_int(norm[e]);
        int pD = atomicAdd(&histD[d >> 8], 1);
        tmpD[pD] = make_int2(((d & 255) << 24) | s, w);
        int pS = atomicAdd(&histS[s >> 8], 1);
        tmpS[pS] = make_int2(((s & 255) << 24) | d, w);
    }
}

// ---------------------------------------------------------------- phase B: per-bucket (256 rows) rowptr build + CSR placement
__global__ __launch_bounds__(256) void k_place(
        const int2* __restrict__ tmp, const int* __restrict__ bb, int nrows, int nbuckets,
        int2* __restrict__ pairs, int* __restrict__ rowptr) {
    int b = blockIdx.x;
    int r0 = b << 8;
    int tid = threadIdx.x, lane = tid & 63, wvi = tid >> 6;
    __shared__ int cnt[256];
    __shared__ int cur[256];
    __shared__ int ws[4];
    cnt[tid] = 0;
    __syncthreads();
    int beg = bb[b], end = bb[b + 1];
    for (int p = beg + tid; p < end; p += 256)
        atomicAdd(&cnt[((unsigned)tmp[p].x) >> 24], 1);
    __syncthreads();
    int c = cnt[tid];
    int x = c;
    #pragma unroll
    for (int o = 1; o < 64; o <<= 1) { int t = __shfl_up(x, o); if (lane >= o) x += t; }
    if (lane == 63) ws[wvi] = x;
    __syncthreads();
    int woff = 0;
    for (int i = 0; i < wvi; i++) woff += ws[i];
    int rpv = beg + woff + x - c;
    if (r0 + tid < nrows) rowptr[r0 + tid] = rpv;
    cur[tid] = rpv;
    if (b == 0 && tid == 0) rowptr[nrows] = bb[nbuckets];
    __syncthreads();
    for (int p = beg + tid; p < end; p += 256) {
        int2 en = tmp[p];
        int l = ((unsigned)en.x) >> 24;
        int pos = atomicAdd(&cur[l], 1);
        pairs[pos] = make_int2(en.x & 0xFFFFFF, en.y);
    }
}

// ---------------------------------------------------------------- weight prep: fp32 [K][Nn] -> FRAGMENT-MAJOR bf16 hi/lo
__global__ void k_prepT(const float* __restrict__ in, int nmat, int K, int Nn,
                        unsigned short* __restrict__ oh, unsigned short* __restrict__ ol) {
    int total = nmat * K * Nn;
    int ntile = Nn >> 4;
    for (int i = blockIdx.x * blockDim.x + threadIdx.x; i < total; i += gridDim.x * blockDim.x) {
        int m = i / (K * Nn), r = i % (K * Nn);
        int k = r / Nn, n = r % Nn;
        float v = in[i];
        unsigned short hb = f2bf(v);
        float lo = v - bf2f(hb);
        int ks = k >> 5, g = (k >> 3) & 3, j = k & 7;
        int nt = n >> 4, rm = n & 15;
        size_t o = (size_t)m * K * Nn + ((size_t)(ks * ntile + nt) * 64 + g * 16 + rm) * 8 + j;
        oh[o] = hb;
        ol[o] = f2bf(lo);
    }
}

// ---------------------------------------------------------------- row prep: center_scale -> dest fp32, then preop->LN->bf16 A (fragment-major)
__global__ __launch_bounds__(256) void k_rowprep(
        const float* __restrict__ in, int S,
        const float* __restrict__ stats,   // null: skip center_scale
        float* __restrict__ dest,          // null: skip fp32 output
        int preop,
        const float* __restrict__ lng, const float* __restrict__ lnb,
        unsigned short* __restrict__ aln) {
    int lane = threadIdx.x & 63, wv = threadIdx.x >> 6;
    int sub = lane >> 4, l16 = lane & 15;
    int row = blockIdx.x * 16 + wv * 4 + sub;
    if (row >= S) return;
    const float* rp = in + (size_t)row * 128 + l16 * 8;
    float4 p0 = *(const float4*)rp;
    float4 p1 = *(const float4*)(rp + 4);
    float v[8] = {p0.x,p0.y,p0.z,p0.w,p1.x,p1.y,p1.z,p1.w};
    if (stats) {
        float inv = stats[128];
        const float4 m0 = *(const float4*)(stats + l16 * 8);
        const float4 m1 = *(const float4*)(stats + l16 * 8 + 4);
        float mu[8] = {m0.x,m0.y,m0.z,m0.w,m1.x,m1.y,m1.z,m1.w};
        #pragma unroll
        for (int j = 0; j < 8; j++) v[j] = (v[j] - mu[j]) * inv;
        if (dest) {
            float* dp = dest + (size_t)row * 128 + l16 * 8;
            *(float4*)dp       = make_float4(v[0], v[1], v[2], v[3]);
            *(float4*)(dp + 4) = make_float4(v[4], v[5], v[6], v[7]);
        }
    }
    float s = 0.f, q = 0.f;
    #pragma unroll
    for (int j = 0; j < 8; j++) {
        float x = v[j];
        if (preop) x = fmaxf(x * BNS, 0.f);
        v[j] = x;
        s += x; q += x * x;
    }
    #pragma unroll
    for (int o = 1; o < 16; o <<= 1) { s += __shfl_xor(s, o); q += __shfl_xor(q, o); }
    float m = s * (1.f / 128.f);
    float var = q * (1.f / 128.f) - m * m;
    float rs = rsqrtf(var + 1e-5f);
    const float4 g0 = *(const float4*)(lng + l16 * 8);
    const float4 g1 = *(const float4*)(lng + l16 * 8 + 4);
    const float4 b0 = *(const float4*)(lnb + l16 * 8);
    const float4 b1 = *(const float4*)(lnb + l16 * 8 + 4);
    float gg[8] = {g0.x,g0.y,g0.z,g0.w,g1.x,g1.y,g1.z,g1.w};
    float bb[8] = {b0.x,b0.y,b0.z,b0.w,b1.x,b1.y,b1.z,b1.w};
    s8v o;
    #pragma unroll
    for (int j = 0; j < 8; j++)
        o[j] = (short)f2bf((v[j] - m) * rs * gg[j] + bb[j]);
    *(s8v*)(aln + a_frag_off(row, l16)) = o;
}

// ---------------------------------------------------------------- MFMA matmul, fragment-major A AND B
template<int NSPLIT, int DEC>
__global__ __launch_bounds__(256, 6) void k_mm16(
        const unsigned short* __restrict__ ainh, const unsigned short* __restrict__ ainl,
        int S,
        const unsigned short* __restrict__ wth, const unsigned short* __restrict__ wtl,
        const float* __restrict__ bias, void* __restrict__ outv,
        float* __restrict__ stats) {
    int lane = threadIdx.x & 63, wv = threadIdx.x >> 6;
    int g = lane >> 4;          // k-group 0..3
    int rm = lane & 15;         // A-row within tile / C-col
    constexpr int NT = NSPLIT ? 2 : 4;
    int rbase, nt0;
    if (NSPLIT) { rbase = blockIdx.x * 16;                  nt0 = wv * 2; }
    else        { rbase = blockIdx.x * 32 + (wv >> 1) * 16; nt0 = (wv & 1) * 4; }

    s8v ah[4], al[4];
    {
        const unsigned short* ap = ainh + (size_t)(rbase >> 4) * 2048 + lane * 8;
        const unsigned short* lp = DEC ? (ainl + (size_t)(rbase >> 4) * 2048 + lane * 8) : ap;
        #pragma unroll
        for (int ks = 0; ks < 4; ks++) {
            ah[ks] = *(const s8v*)(ap + ks * 512);
            if (DEC) al[ks] = *(const s8v*)(lp + ks * 512);
        }
    }

    f4v acch[NT] = {};
    f4v accl[NT] = {};
    #pragma unroll
    for (int ks = 0; ks < 4; ks++) {
        s8v bh[NT], bl[NT];
        #pragma unroll
        for (int ntl = 0; ntl < NT; ntl++) {
            size_t o = ((size_t)(ks * 8 + nt0 + ntl) * 64 + lane) * 8;  // fragment-major, NTILE=8
            bh[ntl] = *(const s8v*)(wth + o);
            bl[ntl] = *(const s8v*)(wtl + o);
        }
        #pragma unroll
        for (int ntl = 0; ntl < NT; ntl++)
            acch[ntl] = mfma16(ah[ks], bh[ntl], acch[ntl]);
        #pragma unroll
        for (int ntl = 0; ntl < NT; ntl++)
            accl[ntl] = mfma16(ah[ks], bl[ntl], accl[ntl]);
        if (DEC) {
            #pragma unroll
            for (int ntl = 0; ntl < NT; ntl++)
                accl[ntl] = mfma16(al[ks], bh[ntl], accl[ntl]);
        }
    }

    __shared__ float cs[129];
    if (DEC && stats) {
        for (int i = threadIdx.x; i < 129; i += 256) cs[i] = 0.f;
        __syncthreads();
    }
    float myq = 0.f;
    #pragma unroll
    for (int ntl = 0; ntl < NT; ntl++) {
        int ntg = nt0 + ntl;
        float bb = bias[ntg * 16 + rm];
        float cp = 0.f;
        #pragma unroll
        for (int r = 0; r < 4; r++) {
            int orow = rbase + g * 4 + r;   // C row mapping
            float val = fmaxf(acch[ntl][r] + accl[ntl][r] + bb, 0.f);
            bool vok = orow < S;
            if (!DEC) {
                unsigned int bits = f2bf(val);
                unsigned int pb = (unsigned int)__shfl_xor((int)bits, 1);
                if (!(lane & 1) && vok) {
                    unsigned int word = bits | (pb << 16);
                    ((unsigned int*)outv)[((size_t)orow * 128 + ntg * 16 + rm) >> 1] = word;
                }
            } else {
                if (vok) ((float*)outv)[(size_t)orow * 128 + ntg * 16 + rm] = val;
                if (stats && vok) { cp += val; myq += val * val; }
            }
        }
        if (DEC && stats) {
            cp += __shfl_xor(cp, 16);
            cp += __shfl_xor(cp, 32);
            if (g == 0) atomicAdd(&cs[ntg * 16 + rm], cp);
        }
    }
    if (DEC && stats) {
        myq = wredf(myq);
        if (lane == 0) atomicAdd(&cs[128], myq);
        __syncthreads();
        float* sb = stats + (size_t)(blockIdx.x & 15) * 132;
        for (int i = threadIdx.x; i < 129; i += 256) {
            float v = cs[i];
            if (v != 0.f) atomicAdd(&sb[i], v);
        }
    }
}

// ---------------------------------------------------------------- CSR gather aggregation -> split hi/lo bf16, fragment-major out
// EP=1: quarter-wave per row, 16 rows/block (latency-light E2V).
// EP=4: full wave per row, 4 quarter-waves on edges p%4, 4 rows/block (deep-MLP V2E).
template<int EP>
__global__ __launch_bounds__(256) void k_aggregate(
        const unsigned short* __restrict__ h, const int* __restrict__ rowptr,
        const int2* __restrict__ pairs,
        unsigned short* __restrict__ aggh, unsigned short* __restrict__ aggl, int T) {
    int lane = threadIdx.x & 63, wv = threadIdx.x >> 6;
    int sub = lane >> 4, l16 = lane & 15;
    int row, es;
    if (EP == 1) { row = blockIdx.x * 16 + wv * 4 + sub; es = 0;   }
    else         { row = blockIdx.x * 4 + wv;            es = sub; }
    if (row >= T) return;
    int beg = rowptr[row], end = rowptr[row + 1];
    float a[8] = {0.f,0.f,0.f,0.f,0.f,0.f,0.f,0.f};
    #pragma unroll 4
    for (int p = beg + es; p < end; p += EP) {
        int2 pr = pairs[p];
        const uint4 v = *(const uint4*)(h + (size_t)pr.x * 128 + l16 * 8);
        float w = __int_as_float(pr.y);
        a[0] = fmaf(w, __uint_as_float(v.x << 16),          a[0]);
        a[1] = fmaf(w, __uint_as_float(v.x & 0xffff0000u),  a[1]);
        a[2] = fmaf(w, __uint_as_float(v.y << 16),          a[2]);
        a[3] = fmaf(w, __uint_as_float(v.y & 0xffff0000u),  a[3]);
        a[4] = fmaf(w, __uint_as_float(v.z << 16),          a[4]);
        a[5] = fmaf(w, __uint_as_float(v.z & 0xffff0000u),  a[5]);
        a[6] = fmaf(w, __uint_as_float(v.w << 16),          a[6]);
        a[7] = fmaf(w, __uint_as_float(v.w & 0xffff0000u),  a[7]);
    }
    if (EP == 4) {
        #pragma unroll
        for (int j = 0; j < 8; j++) {
            a[j] += __shfl_xor(a[j], 16);
            a[j] += __shfl_xor(a[j], 32);
        }
        if (es != 0) return;
    }
    float invc = 1.f / fmaxf((float)(end - beg), 1.f);
    s8v oh, ol;
    #pragma unroll
    for (int j = 0; j < 8; j++) {
        float v = a[j] * invc;
        unsigned short hb = f2bf(v);
        oh[j] = (short)hb;
        ol[j] = (short)f2bf(v - bf2f(hb));
    }
    size_t fo = a_frag_off(row, l16);
    *(s8v*)(aggh + fo) = oh;
    *(s8v*)(aggl + fo) = ol;
}

// ---------------------------------------------------------------- finalize banked center_scale stats: mu[c], inv at [128]
__global__ void k_finalize(float* __restrict__ stats, int n) {
    int c = threadIdx.x;  // 128 threads
    float su = 0.f;
    #pragma unroll
    for (int b = 0; b < 16; b++) su += stats[b * 132 + c];
    float mu = su / (float)n;
    stats[c] = mu;
    float m2 = mu * mu;
    #pragma unroll
    for (int o = 32; o; o >>= 1) m2 += __shfl_xor(m2, o);
    __shared__ float ws2[2];
    if ((c & 63) == 0) ws2[c >> 6] = m2;
    __syncthreads();
    if (c == 0) {
        float qs = 0.f;
        #pragma unroll
        for (int b = 0; b < 16; b++) qs += stats[b * 132 + 128];
        float musq = ws2[0] + ws2[1];
        float msn = qs / (float)n - musq;  // mean ||x_i - mu||^2
        stats[128] = rsqrtf(1e-5f + msn);
    }
}

// ---------------------------------------------------------------- apply center_scale (conv4 tail only)
__global__ void k_apply(const float* __restrict__ in, const float* __restrict__ stats,
                        float* __restrict__ out, int n) {
    size_t i = ((size_t)blockIdx.x * blockDim.x + threadIdx.x) * 4;
    size_t tot = (size_t)n * 128;
    if (i >= tot) return;
    float inv = stats[128];
    int c = (int)(i & 127);
    float4 v = *(const float4*)(in + i);
    v.x = (v.x - stats[c])     * inv;
    v.y = (v.y - stats[c + 1]) * inv;
    v.z = (v.z - stats[c + 2]) * inv;
    v.w = (v.w - stats[c + 3]) * inv;
    *(float4*)(out + i) = v;
}

// ---------------------------------------------------------------- fused classifier: [M,384]@[384,256]+b1 -> LN -> relu -> @[256,2]+b2
__global__ __launch_bounds__(256) void k_cls(
        const float* __restrict__ e0, const float* __restrict__ e1, const float* __restrict__ e2,
        const unsigned short* __restrict__ wth, const unsigned short* __restrict__ wtl,
        const float* __restrict__ b1,
        const float* __restrict__ lng, const float* __restrict__ lnb,
        const float* __restrict__ W2, const float* __restrict__ b2,
        float* __restrict__ out, int M) {
    __shared__ float SC[16 * 260];
    int lane = threadIdx.x & 63, wv = threadIdx.x >> 6;
    int g = lane >> 4, rm = lane & 15;
    int rbase = blockIdx.x * 16;
    int nt0 = wv * 4;
    int row = rbase + rm;
    bool ok = row < M;

    f4v acch[4] = {};
    f4v accl[4] = {};
    #pragma unroll
    for (int ks = 0; ks < 12; ks++) {
        const float* src = (ks < 4) ? e0 : (ks < 8) ? e1 : e2;
        const float* rp = src + (size_t)row * 128 + (ks & 3) * 32 + g * 8;
        float4 p0 = make_float4(0.f,0.f,0.f,0.f), p1 = make_float4(0.f,0.f,0.f,0.f);
        if (ok) { p0 = *(const float4*)rp; p1 = *(const float4*)(rp + 4); }
        float t[8] = {p0.x,p0.y,p0.z,p0.w,p1.x,p1.y,p1.z,p1.w};
        s8v ah, al;
        #pragma unroll
        for (int j = 0; j < 8; j++) {
            unsigned short hb = f2bf(t[j]);
            ah[j] = (short)hb;
            al[j] = (short)f2bf(t[j] - bf2f(hb));
        }
        s8v bh[4], bl[4];
        #pragma unroll
        for (int ntl = 0; ntl < 4; ntl++) {
            size_t o = ((size_t)(ks * 16 + nt0 + ntl) * 64 + lane) * 8;  // fragment-major, NTILE=16
            bh[ntl] = *(const s8v*)(wth + o);
            bl[ntl] = *(const s8v*)(wtl + o);
        }
        #pragma unroll
        for (int ntl = 0; ntl < 4; ntl++) acch[ntl] = mfma16(ah, bh[ntl], acch[ntl]);
        #pragma unroll
        for (int ntl = 0; ntl < 4; ntl++) accl[ntl] = mfma16(al, bh[ntl], accl[ntl]);
        #pragma unroll
        for (int ntl = 0; ntl < 4; ntl++) accl[ntl] = mfma16(ah, bl[ntl], accl[ntl]);
    }

    #pragma unroll
    for (int ntl = 0; ntl < 4; ntl++) {
        int col = (nt0 + ntl) * 16 + rm;
        float bb = b1[col];
        #pragma unroll
        for (int r = 0; r < 4; r++) {
            int lr = g * 4 + r;
            SC[lr * 260 + col] = acch[ntl][r] + accl[ntl][r] + bb;
        }
    }
    __syncthreads();

    #pragma unroll
    for (int rr = 0; rr < 4; rr++) {
        int lr = wv * 4 + rr;
        int orow = rbase + lr;
        const float* sp = SC + lr * 260;
        float v0 = sp[lane], v1 = sp[lane + 64], v2 = sp[lane + 128], v3 = sp[lane + 192];
        float s = wredf(v0 + v1 + v2 + v3);
        float q = wredf(v0 * v0 + v1 * v1 + v2 * v2 + v3 * v3);
        float m = s * (1.f / 256.f);
        float var = q * (1.f / 256.f) - m * m;
        float rs = rsqrtf(var + 1e-5f);
        float h0 = fmaxf((v0 - m) * rs * lng[lane]       + lnb[lane],       0.f);
        float h1 = fmaxf((v1 - m) * rs * lng[lane + 64]  + lnb[lane + 64],  0.f);
        float h2 = fmaxf((v2 - m) * rs * lng[lane + 128] + lnb[lane + 128], 0.f);
        float h3 = fmaxf((v3 - m) * rs * lng[lane + 192] + lnb[lane + 192], 0.f);
        float p0 = h0 * W2[lane * 2]             + h1 * W2[(lane + 64) * 2]
                 + h2 * W2[(lane + 128) * 2]     + h3 * W2[(lane + 192) * 2];
        float p1 = h0 * W2[lane * 2 + 1]         + h1 * W2[(lane + 64) * 2 + 1]
                 + h2 * W2[(lane + 128) * 2 + 1] + h3 * W2[(lane + 192) * 2 + 1];
        p0 = wredf(p0);
        p1 = wredf(p1);
        if (lane == 0 && orow < M) {
            out[(size_t)orow * 2]     = p0 + b2[0];
            out[(size_t)orow * 2 + 1] = p1 + b2[1];
        }
    }
}

// ================================================================ host
extern "C" void kernel_launch(void* const* d_in, const int* in_sizes, int n_in,
                              void* d_out, int out_size, void* d_ws, size_t ws_size,
                              hipStream_t stream) {
    const float* x    = (const float*)d_in[0];
    const int*   srcN = (const int*)d_in[1];
    const int*   dstE = (const int*)d_in[2];
    const float* norm = (const float*)d_in[3];
    const float* elng = (const float*)d_in[4];
    const float* elnb = (const float*)d_in[5];
    const float* eW   = (const float*)d_in[6];
    const float* eB   = (const float*)d_in[7];
    const float* dW   = (const float*)d_in[8];
    const float* dB   = (const float*)d_in[9];
    const float* W1   = (const float*)d_in[10];
    const float* b1   = (const float*)d_in[11];
    const float* clng = (const float*)d_in[12];
    const float* clnb = (const float*)d_in[13];
    const float* W2   = (const float*)d_in[14];
    const float* b2   = (const float*)d_in[15];

    const int N = in_sizes[0] / 128;
    const int E = in_sizes[1];
    const int M = (out_size - N * 128) / 130;
    const int nbD = (M + 255) >> 8;
    const int nbS = (N + 255) >> 8;

    // workspace carve
    char* p = (char*)d_ws;
    auto carve = [&](size_t bytes) { void* q = (void*)p; p += ((bytes + 255) / 256) * 256; return q; };
    int*   minv  = (int*)carve(4);
    int*   bcD   = (int*)carve((size_t)nbD * 4);
    int*   bcS   = (int*)carve((size_t)nbS * 4);
    int*   bbD   = (int*)carve((size_t)(nbD + 1) * 4);
    int*   bbS   = (int*)carve((size_t)(nbS + 1) * 4);
    int*   curD  = (int*)carve((size_t)nbD * 4);
    int*   curS  = (int*)carve((size_t)nbS * 4);
    int*   rpM   = (int*)carve((size_t)(M + 1) * 4);
    int*   rpN   = (int*)carve((size_t)(N + 1) * 4);
    int2*  pairD = (int2*)carve((size_t)E * 8);
    int2*  pairS = (int2*)carve((size_t)E * 8);
    float* stats = (float*)carve(16 * 132 * 4);
    unsigned short* encTh = (unsigned short*)carve((size_t)5 * 16384 * 2);
    unsigned short* encTl = (unsigned short*)carve((size_t)5 * 16384 * 2);
    unsigned short* decTh = (unsigned short*)carve((size_t)5 * 16384 * 2);
    unsigned short* decTl = (unsigned short*)carve((size_t)5 * 16384 * 2);
    unsigned short* w1Th  = (unsigned short*)carve((size_t)384 * 256 * 2);
    unsigned short* w1Tl  = (unsigned short*)carve((size_t)384 * 256 * 2);
    float* hbuf  = (float*)carve((size_t)N * 128 * 4 + 16384);           // dec fp32 out; hb16 overlay
    unsigned short* aggh = (unsigned short*)carve((size_t)N * 128 * 2 + 8192);  // agg hi plane (fragment-major, tile-padded)
    unsigned short* aggl = (unsigned short*)carve((size_t)N * 128 * 2 + 8192);  // agg lo plane; aln16 overlay
    float* e0    = (float*)carve((size_t)M * 128 * 4);
    float* e1    = (float*)carve((size_t)M * 128 * 4);
    unsigned short* hb16  = (unsigned short*)hbuf;     // enc bf16 out (row-major); dead before dec writes hbuf
    unsigned short* aln16 = aggl;                      // LN'd bf16 A (fragment-major); live only while aggl dead
    int2*  tmpD = (int2*)e0;                           // bucket-grouped entries (graph build only)
    int2*  tmpS = (int2*)e1;

    float* outf      = (float*)d_out;
    float* score     = outf;                                   // [M,2]
    float* edge_feat = outf + (size_t)M * 2;                   // [M,128]
    float* node_feat = outf + (size_t)M * 2 + (size_t)M * 128; // [N,128]

    // ---- weight prep (transpose + split-bf16, fragment-major)
    k_prepT<<<320, 256, 0, stream>>>(eW, 5, 128, 128, encTh, encTl);
    k_prepT<<<320, 256, 0, stream>>>(dW, 5, 128, 128, decTh, decTl);
    k_prepT<<<384, 256, 0, stream>>>(W1, 1, 384, 256, w1Th, w1Tl);

    // ---- graph structure: bucket count -> bucket scan -> partition -> per-bucket rowptr+CSR place
    hipMemsetAsync(minv, 0x7f, 4, stream);
    hipMemsetAsync(bcD, 0, (size_t)nbD * 4, stream);
    hipMemsetAsync(bcS, 0, (size_t)nbS * 4, stream);
    k_min<<<256, 256, 0, stream>>>(dstE, E, minv);
    k_bcount<<<(E + BC_CHUNK - 1) / BC_CHUNK, 256, 0, stream>>>(dstE, srcN, minv, E, nbD, nbS, bcD, bcS);
    k_scan<<<1, 1024, 0, stream>>>(bcD, nbD, bbD);
    k_scan<<<1, 1024, 0, stream>>>(bcS, nbS, bbS);
    k_curinit<<<(max(nbD, nbS) + 255) / 256, 256, 0, stream>>>(bbD, bbS, nbD, nbS, curD, curS);
    k_part<<<(E + PART_CHUNK - 1) / PART_CHUNK, 256, 0, stream>>>(
        dstE, srcN, norm, minv, E, nbD, nbS, curD, curS, tmpD, tmpS);
    k_place<<<nbD, 256, 0, stream>>>(tmpD, bbD, M, nbD, pairD, rpM);
    k_place<<<nbS, 256, 0, stream>>>(tmpS, bbS, N, nbS, pairS, rpN);

    // ---- matmul dispatch helpers
    auto mmenc = [&](int rows, int k) {
        if (rows > 30000)
            k_mm16<0,0><<<(rows + 31) / 32, 256, 0, stream>>>(
                aln16, nullptr, rows, encTh + (size_t)k * 16384, encTl + (size_t)k * 16384,
                eB + (size_t)k * 128, hb16, nullptr);
        else
            k_mm16<1,0><<<(rows + 15) / 16, 256, 0, stream>>>(
                aln16, nullptr, rows, encTh + (size_t)k * 16384, encTl + (size_t)k * 16384,
                eB + (size_t)k * 128, hb16, nullptr);
    };
    auto mmdec = [&](int rows, int k) {
        if (rows > 30000)
            k_mm16<0,1><<<(rows + 31) / 32, 256, 0, stream>>>(
                aggh, aggl, rows, decTh + (size_t)k * 16384, decTl + (size_t)k * 16384,
                dB + (size_t)k * 128, hbuf, stats);
        else
            k_mm16<1,1><<<(rows + 15) / 16, 256, 0, stream>>>(
                aggh, aggl, rows, decTh + (size_t)k * 16384, decTl + (size_t)k * 16384,
                dB + (size_t)k * 128, hbuf, stats);
    };

    // ---- one half-conv: enc(bf16 A) -> CSR-mean agg (split hi/lo) -> dec(fused stats) -> rowprep tail
    auto conv = [&](int S, int T, int k, int v2e, float* dest) {
        mmenc(S, k);
        if (v2e)
            k_aggregate<4><<<(T + 3) / 4, 256, 0, stream>>>(hb16, rpM, pairD, aggh, aggl, T);
        else
            k_aggregate<1><<<(T + 15) / 16, 256, 0, stream>>>(hb16, rpN, pairS, aggh, aggl, T);
        hipMemsetAsync(stats, 0, 16 * 132 * 4, stream);
        mmdec(T, k);
        k_finalize<<<1, 128, 0, stream>>>(stats, T);
        if (k < 4) {
            // fused: center_scale -> dest (skipped if dead), then preop+LN+bf16 for conv k+1's enc A
            k_rowprep<<<(T + 15) / 16, 256, 0, stream>>>(
                hbuf, T, stats, dest, 1,
                elng + (size_t)(k + 1) * 128, elnb + (size_t)(k + 1) * 128, aln16);
        } else {
            size_t tot4 = ((size_t)T * 128) / 4;
            k_apply<<<(unsigned)((tot4 + 255) / 256), 256, 0, stream>>>(hbuf, stats, dest, T);
        }
    };

    // conv0's enc A from raw x (no preop, LN params k=0)
    k_rowprep<<<(N + 15) / 16, 256, 0, stream>>>(x, N, nullptr, nullptr, 0, elng, elnb, aln16);
    conv(N, M, 0, 1, e0);         // V2E0  (tail preps conv1's A at M rows)
    conv(M, N, 1, 0, nullptr);    // E2V0  (nf1 is dead — overwritten by conv3 before any read)
    conv(N, M, 2, 1, e1);         // V2E1
    conv(M, N, 3, 0, node_feat);  // E2V1 -> final node_feat
    conv(N, M, 4, 1, edge_feat);  // V2E2 -> final edge_feat (plain apply tail)

    k_cls<<<(M + 15) / 16, 256, 0, stream>>>(
        e0, e1, edge_feat, w1Th, w1Tl, b1, clng, clnb, W2, b2, score, M);
}

// Round 19
// 591.297 us; speedup vs baseline: 1.0793x; 1.0005x over previous
//
#include <hip/hip_runtime.h>
#include <math.h>

#define BNS 0.9999950000374997f  /* 1/sqrt(1+1e-5) */

typedef short s8v __attribute__((ext_vector_type(8)));
typedef float f4v __attribute__((ext_vector_type(4)));

// fragment-major A offset: quarter-wave lane l16 owns cols [l16*8, l16*8+8) of `row`
static __device__ __forceinline__ size_t a_frag_off(int row, int l16) {
    return ((size_t)(row >> 4) * 4 + (l16 >> 2)) * 512 + (size_t)(((l16 & 3) << 4) + (row & 15)) * 8;
}

// ---------------------------------------------------------------- utilities
static __device__ __forceinline__ float wredf(float v) {
    #pragma unroll
    for (int o = 32; o; o >>= 1) v += __shfl_xor(v, o);
    return v;
}

static __device__ __forceinline__ unsigned short f2bf(float f) {
    unsigned int u = __float_as_uint(f);
    u = (u + 0x7fffu + ((u >> 16) & 1u)) >> 16;  // RNE
    return (unsigned short)u;
}

static __device__ __forceinline__ float bf2f(unsigned short b) {
    return __uint_as_float((unsigned int)b << 16);
}

static __device__ __forceinline__ f4v mfma16(s8v a, s8v b, f4v c) {
    return __builtin_amdgcn_mfma_f32_16x16x32_bf16(a, b, c, 0, 0, 0);
}

// ---------------------------------------------------------------- min of dst
__global__ void k_min(const int* __restrict__ d, int E, int* __restrict__ mn) {
    int i = blockIdx.x * blockDim.x + threadIdx.x;
    int v = 0x7FFFFFFF;
    for (; i < E; i += gridDim.x * blockDim.x) v = min(v, d[i]);
    #pragma unroll
    for (int o = 32; o; o >>= 1) v = min(v, __shfl_xor(v, o));
    if ((threadIdx.x & 63) == 0) atomicMin(mn, v);
}

// ---------------------------------------------------------------- bucket histogram (256-row buckets; LDS-aggregated)
#define BC_CHUNK 4096
__global__ __launch_bounds__(256) void k_bcount(
        const int* __restrict__ dst, const int* __restrict__ src,
        const int* __restrict__ minbuf, int E, int nbD, int nbS,
        int* __restrict__ bcD, int* __restrict__ bcS) {
    __shared__ int hD[128];
    __shared__ int hS[512];
    int tid = threadIdx.x;
    int mn = minbuf[0];
    int base = blockIdx.x * BC_CHUNK;
    int limit = min(base + BC_CHUNK, E);
    for (int i = tid; i < nbD; i += 256) hD[i] = 0;
    for (int i = tid; i < nbS; i += 256) hS[i] = 0;
    __syncthreads();
    for (int e = base + tid; e < limit; e += 256) {
        atomicAdd(&hD[(dst[e] - mn) >> 8], 1);
        atomicAdd(&hS[src[e] >> 8], 1);
    }
    __syncthreads();
    for (int i = tid; i < nbD; i += 256) { int c = hD[i]; if (c) atomicAdd(&bcD[i], c); }
    for (int i = tid; i < nbS; i += 256) { int c = hS[i]; if (c) atomicAdd(&bcS[i], c); }
}

// ---------------------------------------------------------------- small scan (single block); also fills cursor copy
__global__ __launch_bounds__(1024) void k_scan(const int* __restrict__ cnt, int n,
                                               int* __restrict__ rowptr, int* __restrict__ cur) {
    __shared__ int wsum[16];
    __shared__ int carry;
    int tid = threadIdx.x, lane = tid & 63, wv = tid >> 6;
    if (tid == 0) carry = 0;
    __syncthreads();
    for (int base = 0; base < n; base += 1024) {
        int i = base + tid;
        int v = (i < n) ? cnt[i] : 0;
        int x = v;
        #pragma unroll
        for (int o = 1; o < 64; o <<= 1) { int t = __shfl_up(x, o); if (lane >= o) x += t; }
        if (lane == 63) wsum[wv] = x;
        __syncthreads();
        if (tid < 16) {
            int s = wsum[tid];
            #pragma unroll
            for (int o = 1; o < 16; o <<= 1) { int t = __shfl_up(s, o); if (tid >= o) s += t; }
            wsum[tid] = s;
        }
        __syncthreads();
        int woff = (wv == 0) ? 0 : wsum[wv - 1];
        int excl = carry + woff + x - v;
        if (i < n) {
            rowptr[i] = excl;
            if (cur) cur[i] = excl;
        }
        __syncthreads();
        if (tid == 1023) carry = carry + wsum[15];
        __syncthreads();
    }
    if (tid == 0) rowptr[n] = carry;
}

// ---------------------------------------------------------------- phase A: bucket partition with run reservation
// Entries packed: .x = (local_row<<24) | gather_row (local<256, gather<2^24).
#define PART_CHUNK 4096
__global__ __launch_bounds__(256) void k_part(
        const int* __restrict__ dst, const int* __restrict__ src,
        const float* __restrict__ norm, const int* __restrict__ minbuf, int E,
        int nbD, int nbS, int* __restrict__ curD, int* __restrict__ curS,
        int2* __restrict__ tmpD, int2* __restrict__ tmpS) {
    __shared__ int histD[128];
    __shared__ int histS[512];
    int tid = threadIdx.x;
    int mn = minbuf[0];
    int base = blockIdx.x * PART_CHUNK;
    int limit = min(base + PART_CHUNK, E);
    for (int i = tid; i < nbD; i += 256) histD[i] = 0;
    for (int i = tid; i < nbS; i += 256) histS[i] = 0;
    __syncthreads();
    for (int e = base + tid; e < limit; e += 256) {
        int d = dst[e] - mn;
        int s = src[e];
        atomicAdd(&histD[d >> 8], 1);
        atomicAdd(&histS[s >> 8], 1);
    }
    __syncthreads();
    for (int i = tid; i < nbD; i += 256) {
        int c = histD[i];
        histD[i] = c ? atomicAdd(&curD[i], c) : 0;
    }
    for (int i = tid; i < nbS; i += 256) {
        int c = histS[i];
        histS[i] = c ? atomicAdd(&curS[i], c) : 0;
    }
    __syncthreads();
    for (int e = base + tid; e < limit; e += 256) {
        int d = dst[e] - mn;
        int s = src[e];
        int w = __float_as_int(norm[e]);
        int pD = atomicAdd(&histD[d >> 8], 1);
        tmpD[pD] = make_int2(((d & 255) << 24) | s, w);
        int pS = atomicAdd(&histS[s >> 8], 1);
        tmpS[pS] = make_int2(((s & 255) << 24) | d, w);
    }
}

// ---------------------------------------------------------------- phase B: per-bucket (256 rows) rowptr build + CSR placement
__global__ __launch_bounds__(256) void k_place(
        const int2* __restrict__ tmp, const int* __restrict__ bb, int nrows, int nbuckets,
        int2* __restrict__ pairs, int* __restrict__ rowptr) {
    int b = blockIdx.x;
    int r0 = b << 8;
    int tid = threadIdx.x, lane = tid & 63, wvi = tid >> 6;
    __shared__ int cnt[256];
    __shared__ int cur[256];
    __shared__ int ws[4];
    cnt[tid] = 0;
    __syncthreads();
    int beg = bb[b], end = bb[b + 1];
    for (int p = beg + tid; p < end; p += 256)
        atomicAdd(&cnt[((unsigned)tmp[p].x) >> 24], 1);
    __syncthreads();
    int c = cnt[tid];
    int x = c;
    #pragma unroll
    for (int o = 1; o < 64; o <<= 1) { int t = __shfl_up(x, o); if (lane >= o) x += t; }
    if (lane == 63) ws[wvi] = x;
    __syncthreads();
    int woff = 0;
    for (int i = 0; i < wvi; i++) woff += ws[i];
    int rpv = beg + woff + x - c;
    if (r0 + tid < nrows) rowptr[r0 + tid] = rpv;
    cur[tid] = rpv;
    if (b == 0 && tid == 0) rowptr[nrows] = bb[nbuckets];
    __syncthreads();
    for (int p = beg + tid; p < end; p += 256) {
        int2 en = tmp[p];
        int l = ((unsigned)en.x) >> 24;
        int pos = atomicAdd(&cur[l], 1);
        pairs[pos] = make_int2(en.x & 0xFFFFFF, en.y);
    }
}

// ---------------------------------------------------------------- fused weight prep: all three weight sets, fragment-major hi/lo
static __device__ __forceinline__ void prep_store(
        float v, int m, int k, int n, int K, int Nn,
        unsigned short* __restrict__ oh, unsigned short* __restrict__ ol) {
    unsigned short hb = f2bf(v);
    float lo = v - bf2f(hb);
    int ntile = Nn >> 4;
    int ks = k >> 5, g = (k >> 3) & 3, j = k & 7;
    int nt = n >> 4, rm = n & 15;
    size_t o = (size_t)m * K * Nn + ((size_t)(ks * ntile + nt) * 64 + g * 16 + rm) * 8 + j;
    oh[o] = hb;
    ol[o] = f2bf(lo);
}

__global__ __launch_bounds__(256) void k_prepAll(
        const float* __restrict__ eW, const float* __restrict__ dW, const float* __restrict__ W1,
        unsigned short* __restrict__ encTh, unsigned short* __restrict__ encTl,
        unsigned short* __restrict__ decTh, unsigned short* __restrict__ decTl,
        unsigned short* __restrict__ w1Th,  unsigned short* __restrict__ w1Tl) {
    const int ENC = 5 * 16384, DEC = 5 * 16384, WC = 384 * 256;
    int total = ENC + DEC + WC;
    for (int i = blockIdx.x * blockDim.x + threadIdx.x; i < total; i += gridDim.x * blockDim.x) {
        if (i < ENC) {
            int m = i / 16384, r = i % 16384;
            prep_store(eW[i], m, r / 128, r % 128, 128, 128, encTh, encTl);
        } else if (i < ENC + DEC) {
            int t = i - ENC;
            int m = t / 16384, r = t % 16384;
            prep_store(dW[t], m, r / 128, r % 128, 128, 128, decTh, decTl);
        } else {
            int t = i - ENC - DEC;
            prep_store(W1[t], 0, t / 256, t % 256, 384, 256, w1Th, w1Tl);
        }
    }
}

// ---------------------------------------------------------------- row prep: center_scale -> dest fp32, then preop->LN->bf16 A (fragment-major)
__global__ __launch_bounds__(256) void k_rowprep(
        const float* __restrict__ in, int S,
        const float* __restrict__ fstat,   // null: skip center_scale
        float* __restrict__ dest,          // null: skip fp32 output
        int preop,
        const float* __restrict__ lng, const float* __restrict__ lnb,
        unsigned short* __restrict__ aln) {
    int lane = threadIdx.x & 63, wv = threadIdx.x >> 6;
    int sub = lane >> 4, l16 = lane & 15;
    int row = blockIdx.x * 16 + wv * 4 + sub;
    if (row >= S) return;
    const float* rp = in + (size_t)row * 128 + l16 * 8;
    float4 p0 = *(const float4*)rp;
    float4 p1 = *(const float4*)(rp + 4);
    float v[8] = {p0.x,p0.y,p0.z,p0.w,p1.x,p1.y,p1.z,p1.w};
    if (fstat) {
        float inv = fstat[128];
        const float4 m0 = *(const float4*)(fstat + l16 * 8);
        const float4 m1 = *(const float4*)(fstat + l16 * 8 + 4);
        float mu[8] = {m0.x,m0.y,m0.z,m0.w,m1.x,m1.y,m1.z,m1.w};
        #pragma unroll
        for (int j = 0; j < 8; j++) v[j] = (v[j] - mu[j]) * inv;
        if (dest) {
            float* dp = dest + (size_t)row * 128 + l16 * 8;
            *(float4*)dp       = make_float4(v[0], v[1], v[2], v[3]);
            *(float4*)(dp + 4) = make_float4(v[4], v[5], v[6], v[7]);
        }
    }
    float s = 0.f, q = 0.f;
    #pragma unroll
    for (int j = 0; j < 8; j++) {
        float x = v[j];
        if (preop) x = fmaxf(x * BNS, 0.f);
        v[j] = x;
        s += x; q += x * x;
    }
    #pragma unroll
    for (int o = 1; o < 16; o <<= 1) { s += __shfl_xor(s, o); q += __shfl_xor(q, o); }
    float m = s * (1.f / 128.f);
    float var = q * (1.f / 128.f) - m * m;
    float rs = rsqrtf(var + 1e-5f);
    const float4 g0 = *(const float4*)(lng + l16 * 8);
    const float4 g1 = *(const float4*)(lng + l16 * 8 + 4);
    const float4 b0 = *(const float4*)(lnb + l16 * 8);
    const float4 b1 = *(const float4*)(lnb + l16 * 8 + 4);
    float gg[8] = {g0.x,g0.y,g0.z,g0.w,g1.x,g1.y,g1.z,g1.w};
    float bb[8] = {b0.x,b0.y,b0.z,b0.w,b1.x,b1.y,b1.z,b1.w};
    s8v o;
    #pragma unroll
    for (int j = 0; j < 8; j++)
        o[j] = (short)f2bf((v[j] - m) * rs * gg[j] + bb[j]);
    *(s8v*)(aln + a_frag_off(row, l16)) = o;
}

// ---------------------------------------------------------------- MFMA matmul, fragment-major A AND B
template<int NSPLIT, int DEC>
__global__ __launch_bounds__(256, 6) void k_mm16(
        const unsigned short* __restrict__ ainh, const unsigned short* __restrict__ ainl,
        int S,
        const unsigned short* __restrict__ wth, const unsigned short* __restrict__ wtl,
        const float* __restrict__ bias, void* __restrict__ outv,
        float* __restrict__ stats) {
    int lane = threadIdx.x & 63, wv = threadIdx.x >> 6;
    int g = lane >> 4;          // k-group 0..3
    int rm = lane & 15;         // A-row within tile / C-col
    constexpr int NT = NSPLIT ? 2 : 4;
    int rbase, nt0;
    if (NSPLIT) { rbase = blockIdx.x * 16;                  nt0 = wv * 2; }
    else        { rbase = blockIdx.x * 32 + (wv >> 1) * 16; nt0 = (wv & 1) * 4; }

    s8v ah[4], al[4];
    {
        const unsigned short* ap = ainh + (size_t)(rbase >> 4) * 2048 + lane * 8;
        const unsigned short* lp = DEC ? (ainl + (size_t)(rbase >> 4) * 2048 + lane * 8) : ap;
        #pragma unroll
        for (int ks = 0; ks < 4; ks++) {
            ah[ks] = *(const s8v*)(ap + ks * 512);
            if (DEC) al[ks] = *(const s8v*)(lp + ks * 512);
        }
    }

    f4v acch[NT] = {};
    f4v accl[NT] = {};
    #pragma unroll
    for (int ks = 0; ks < 4; ks++) {
        s8v bh[NT], bl[NT];
        #pragma unroll
        for (int ntl = 0; ntl < NT; ntl++) {
            size_t o = ((size_t)(ks * 8 + nt0 + ntl) * 64 + lane) * 8;  // fragment-major, NTILE=8
            bh[ntl] = *(const s8v*)(wth + o);
            bl[ntl] = *(const s8v*)(wtl + o);
        }
        #pragma unroll
        for (int ntl = 0; ntl < NT; ntl++)
            acch[ntl] = mfma16(ah[ks], bh[ntl], acch[ntl]);
        #pragma unroll
        for (int ntl = 0; ntl < NT; ntl++)
            accl[ntl] = mfma16(ah[ks], bl[ntl], accl[ntl]);
        if (DEC) {
            #pragma unroll
            for (int ntl = 0; ntl < NT; ntl++)
                accl[ntl] = mfma16(al[ks], bh[ntl], accl[ntl]);
        }
    }

    __shared__ float cs[129];
    if (DEC && stats) {
        for (int i = threadIdx.x; i < 129; i += 256) cs[i] = 0.f;
        __syncthreads();
    }
    float myq = 0.f;
    #pragma unroll
    for (int ntl = 0; ntl < NT; ntl++) {
        int ntg = nt0 + ntl;
        float bb = bias[ntg * 16 + rm];
        float cp = 0.f;
        #pragma unroll
        for (int r = 0; r < 4; r++) {
            int orow = rbase + g * 4 + r;   // C row mapping
            float val = fmaxf(acch[ntl][r] + accl[ntl][r] + bb, 0.f);
            bool vok = orow < S;
            if (!DEC) {
                unsigned int bits = f2bf(val);
                unsigned int pb = (unsigned int)__shfl_xor((int)bits, 1);
                if (!(lane & 1) && vok) {
                    unsigned int word = bits | (pb << 16);
                    ((unsigned int*)outv)[((size_t)orow * 128 + ntg * 16 + rm) >> 1] = word;
                }
            } else {
                if (vok) ((float*)outv)[(size_t)orow * 128 + ntg * 16 + rm] = val;
                if (stats && vok) { cp += val; myq += val * val; }
            }
        }
        if (DEC && stats) {
            cp += __shfl_xor(cp, 16);
            cp += __shfl_xor(cp, 32);
            if (g == 0) atomicAdd(&cs[ntg * 16 + rm], cp);
        }
    }
    if (DEC && stats) {
        myq = wredf(myq);
        if (lane == 0) atomicAdd(&cs[128], myq);
        __syncthreads();
        float* sb = stats + (size_t)(blockIdx.x & 15) * 132;
        for (int i = threadIdx.x; i < 129; i += 256) {
            float v = cs[i];
            if (v != 0.f) atomicAdd(&sb[i], v);
        }
    }
}

// ---------------------------------------------------------------- CSR gather aggregation -> split hi/lo bf16, fragment-major out
// EP=1: quarter-wave per row, 16 rows/block (latency-light E2V).
// EP=4: full wave per row, 4 quarter-waves on edges p%4, 4 rows/block (deep-MLP V2E).
template<int EP>
__global__ __launch_bounds__(256) void k_aggregate(
        const unsigned short* __restrict__ h, const int* __restrict__ rowptr,
        const int2* __restrict__ pairs,
        unsigned short* __restrict__ aggh, unsigned short* __restrict__ aggl, int T) {
    int lane = threadIdx.x & 63, wv = threadIdx.x >> 6;
    int sub = lane >> 4, l16 = lane & 15;
    int row, es;
    if (EP == 1) { row = blockIdx.x * 16 + wv * 4 + sub; es = 0;   }
    else         { row = blockIdx.x * 4 + wv;            es = sub; }
    if (row >= T) return;
    int beg = rowptr[row], end = rowptr[row + 1];
    float a[8] = {0.f,0.f,0.f,0.f,0.f,0.f,0.f,0.f};
    #pragma unroll 4
    for (int p = beg + es; p < end; p += EP) {
        int2 pr = pairs[p];
        const uint4 v = *(const uint4*)(h + (size_t)pr.x * 128 + l16 * 8);
        float w = __int_as_float(pr.y);
        a[0] = fmaf(w, __uint_as_float(v.x << 16),          a[0]);
        a[1] = fmaf(w, __uint_as_float(v.x & 0xffff0000u),  a[1]);
        a[2] = fmaf(w, __uint_as_float(v.y << 16),          a[2]);
        a[3] = fmaf(w, __uint_as_float(v.y & 0xffff0000u),  a[3]);
        a[4] = fmaf(w, __uint_as_float(v.z << 16),          a[4]);
        a[5] = fmaf(w, __uint_as_float(v.z & 0xffff0000u),  a[5]);
        a[6] = fmaf(w, __uint_as_float(v.w << 16),          a[6]);
        a[7] = fmaf(w, __uint_as_float(v.w & 0xffff0000u),  a[7]);
    }
    if (EP == 4) {
        #pragma unroll
        for (int j = 0; j < 8; j++) {
            a[j] += __shfl_xor(a[j], 16);
            a[j] += __shfl_xor(a[j], 32);
        }
        if (es != 0) return;
    }
    float invc = 1.f / fmaxf((float)(end - beg), 1.f);
    s8v oh, ol;
    #pragma unroll
    for (int j = 0; j < 8; j++) {
        float v = a[j] * invc;
        unsigned short hb = f2bf(v);
        oh[j] = (short)hb;
        ol[j] = (short)f2bf(v - bf2f(hb));
    }
    size_t fo = a_frag_off(row, l16);
    *(s8v*)(aggh + fo) = oh;
    *(s8v*)(aggl + fo) = ol;
}

// ---------------------------------------------------------------- finalize banked stats -> fstat; zero banks for next conv
__global__ void k_finalize(float* __restrict__ stats, float* __restrict__ fstat, int n) {
    int c = threadIdx.x;  // 128 threads
    float su = 0.f;
    #pragma unroll
    for (int b = 0; b < 16; b++) su += stats[b * 132 + c];
    float mu = su / (float)n;
    fstat[c] = mu;
    float m2 = mu * mu;
    #pragma unroll
    for (int o = 32; o; o >>= 1) m2 += __shfl_xor(m2, o);
    __shared__ float ws2[2];
    if ((c & 63) == 0) ws2[c >> 6] = m2;
    __syncthreads();
    if (c == 0) {
        float qs = 0.f;
        #pragma unroll
        for (int b = 0; b < 16; b++) qs += stats[b * 132 + 128];
        float musq = ws2[0] + ws2[1];
        float msn = qs / (float)n - musq;  // mean ||x_i - mu||^2
        fstat[128] = rsqrtf(1e-5f + msn);
    }
    // zero banks (same-thread read-then-zero per slot; no cross-thread hazard)
    #pragma unroll
    for (int b = 0; b < 16; b++) {
        stats[b * 132 + c] = 0.f;
        if (c == 0) stats[b * 132 + 128] = 0.f;
    }
}

// ---------------------------------------------------------------- apply center_scale (conv4 tail only)
__global__ void k_apply(const float* __restrict__ in, const float* __restrict__ fstat,
                        float* __restrict__ out, int n) {
    size_t i = ((size_t)blockIdx.x * blockDim.x + threadIdx.x) * 4;
    size_t tot = (size_t)n * 128;
    if (i >= tot) return;
    float inv = fstat[128];
    int c = (int)(i & 127);
    float4 v = *(const float4*)(in + i);
    v.x = (v.x - fstat[c])     * inv;
    v.y = (v.y - fstat[c + 1]) * inv;
    v.z = (v.z - fstat[c + 2]) * inv;
    v.w = (v.w - fstat[c + 3]) * inv;
    *(float4*)(out + i) = v;
}

// ---------------------------------------------------------------- fused classifier: [M,384]@[384,256]+b1 -> LN -> relu -> @[256,2]+b2
__global__ __launch_bounds__(256) void k_cls(
        const float* __restrict__ e0, const float* __restrict__ e1, const float* __restrict__ e2,
        const unsigned short* __restrict__ wth, const unsigned short* __restrict__ wtl,
        const float* __restrict__ b1,
        const float* __restrict__ lng, const float* __restrict__ lnb,
        const float* __restrict__ W2, const float* __restrict__ b2,
        float* __restrict__ out, int M) {
    __shared__ float SC[16 * 260];
    int lane = threadIdx.x & 63, wv = threadIdx.x >> 6;
    int g = lane >> 4, rm = lane & 15;
    int rbase = blockIdx.x * 16;
    int nt0 = wv * 4;
    int row = rbase + rm;
    bool ok = row < M;

    f4v acch[4] = {};
    f4v accl[4] = {};
    #pragma unroll
    for (int ks = 0; ks < 12; ks++) {
        const float* src = (ks < 4) ? e0 : (ks < 8) ? e1 : e2;
        const float* rp = src + (size_t)row * 128 + (ks & 3) * 32 + g * 8;
        float4 p0 = make_float4(0.f,0.f,0.f,0.f), p1 = make_float4(0.f,0.f,0.f,0.f);
        if (ok) { p0 = *(const float4*)rp; p1 = *(const float4*)(rp + 4); }
        float t[8] = {p0.x,p0.y,p0.z,p0.w,p1.x,p1.y,p1.z,p1.w};
        s8v ah, al;
        #pragma unroll
        for (int j = 0; j < 8; j++) {
            unsigned short hb = f2bf(t[j]);
            ah[j] = (short)hb;
            al[j] = (short)f2bf(t[j] - bf2f(hb));
        }
        s8v bh[4], bl[4];
        #pragma unroll
        for (int ntl = 0; ntl < 4; ntl++) {
            size_t o = ((size_t)(ks * 16 + nt0 + ntl) * 64 + lane) * 8;  // fragment-major, NTILE=16
            bh[ntl] = *(const s8v*)(wth + o);
            bl[ntl] = *(const s8v*)(wtl + o);
        }
        #pragma unroll
        for (int ntl = 0; ntl < 4; ntl++) acch[ntl] = mfma16(ah, bh[ntl], acch[ntl]);
        #pragma unroll
        for (int ntl = 0; ntl < 4; ntl++) accl[ntl] = mfma16(al, bh[ntl], accl[ntl]);
        #pragma unroll
        for (int ntl = 0; ntl < 4; ntl++) accl[ntl] = mfma16(ah, bl[ntl], accl[ntl]);
    }

    #pragma unroll
    for (int ntl = 0; ntl < 4; ntl++) {
        int col = (nt0 + ntl) * 16 + rm;
        float bb = b1[col];
        #pragma unroll
        for (int r = 0; r < 4; r++) {
            int lr = g * 4 + r;
            SC[lr * 260 + col] = acch[ntl][r] + accl[ntl][r] + bb;
        }
    }
    __syncthreads();

    #pragma unroll
    for (int rr = 0; rr < 4; rr++) {
        int lr = wv * 4 + rr;
        int orow = rbase + lr;
        const float* sp = SC + lr * 260;
        float v0 = sp[lane], v1 = sp[lane + 64], v2 = sp[lane + 128], v3 = sp[lane + 192];
        float s = wredf(v0 + v1 + v2 + v3);
        float q = wredf(v0 * v0 + v1 * v1 + v2 * v2 + v3 * v3);
        float m = s * (1.f / 256.f);
        float var = q * (1.f / 256.f) - m * m;
        float rs = rsqrtf(var + 1e-5f);
        float h0 = fmaxf((v0 - m) * rs * lng[lane]       + lnb[lane],       0.f);
        float h1 = fmaxf((v1 - m) * rs * lng[lane + 64]  + lnb[lane + 64],  0.f);
        float h2 = fmaxf((v2 - m) * rs * lng[lane + 128] + lnb[lane + 128], 0.f);
        float h3 = fmaxf((v3 - m) * rs * lng[lane + 192] + lnb[lane + 192], 0.f);
        float p0 = h0 * W2[lane * 2]             + h1 * W2[(lane + 64) * 2]
                 + h2 * W2[(lane + 128) * 2]     + h3 * W2[(lane + 192) * 2];
        float p1 = h0 * W2[lane * 2 + 1]         + h1 * W2[(lane + 64) * 2 + 1]
                 + h2 * W2[(lane + 128) * 2 + 1] + h3 * W2[(lane + 192) * 2 + 1];
        p0 = wredf(p0);
        p1 = wredf(p1);
        if (lane == 0 && orow < M) {
            out[(size_t)orow * 2]     = p0 + b2[0];
            out[(size_t)orow * 2 + 1] = p1 + b2[1];
        }
    }
}

// ================================================================ host
extern "C" void kernel_launch(void* const* d_in, const int* in_sizes, int n_in,
                              void* d_out, int out_size, void* d_ws, size_t ws_size,
                              hipStream_t stream) {
    const float* x    = (const float*)d_in[0];
    const int*   srcN = (const int*)d_in[1];
    const int*   dstE = (const int*)d_in[2];
    const float* norm = (const float*)d_in[3];
    const float* elng = (const float*)d_in[4];
    const float* elnb = (const float*)d_in[5];
    const float* eW   = (const float*)d_in[6];
    const float* eB   = (const float*)d_in[7];
    const float* dW   = (const float*)d_in[8];
    const float* dB   = (const float*)d_in[9];
    const float* W1   = (const float*)d_in[10];
    const float* b1   = (const float*)d_in[11];
    const float* clng = (const float*)d_in[12];
    const float* clnb = (const float*)d_in[13];
    const float* W2   = (const float*)d_in[14];
    const float* b2   = (const float*)d_in[15];

    const int N = in_sizes[0] / 128;
    const int E = in_sizes[1];
    const int M = (out_size - N * 128) / 130;
    const int nbD = (M + 255) >> 8;
    const int nbS = (N + 255) >> 8;

    // workspace carve
    char* p = (char*)d_ws;
    auto carve = [&](size_t bytes) { void* q = (void*)p; p += ((bytes + 255) / 256) * 256; return q; };
    int*   minv  = (int*)carve(4);
    int*   bcD   = (int*)carve((size_t)nbD * 4);
    int*   bcS   = (int*)carve((size_t)nbS * 4);
    int*   bbD   = (int*)carve((size_t)(nbD + 1) * 4);
    int*   bbS   = (int*)carve((size_t)(nbS + 1) * 4);
    int*   curD  = (int*)carve((size_t)nbD * 4);
    int*   curS  = (int*)carve((size_t)nbS * 4);
    int*   rpM   = (int*)carve((size_t)(M + 1) * 4);
    int*   rpN   = (int*)carve((size_t)(N + 1) * 4);
    int2*  pairD = (int2*)carve((size_t)E * 8);
    int2*  pairS = (int2*)carve((size_t)E * 8);
    float* stats = (float*)carve(16 * 132 * 4);
    float* fstat = (float*)carve(132 * 4);
    unsigned short* encTh = (unsigned short*)carve((size_t)5 * 16384 * 2);
    unsigned short* encTl = (unsigned short*)carve((size_t)5 * 16384 * 2);
    unsigned short* decTh = (unsigned short*)carve((size_t)5 * 16384 * 2);
    unsigned short* decTl = (unsigned short*)carve((size_t)5 * 16384 * 2);
    unsigned short* w1Th  = (unsigned short*)carve((size_t)384 * 256 * 2);
    unsigned short* w1Tl  = (unsigned short*)carve((size_t)384 * 256 * 2);
    float* hbuf  = (float*)carve((size_t)N * 128 * 4 + 16384);           // dec fp32 out; hb16 overlay
    unsigned short* aggh = (unsigned short*)carve((size_t)N * 128 * 2 + 8192);  // agg hi plane (fragment-major, tile-padded)
    unsigned short* aggl = (unsigned short*)carve((size_t)N * 128 * 2 + 8192);  // agg lo plane; aln16 overlay
    float* e0    = (float*)carve((size_t)M * 128 * 4);
    float* e1    = (float*)carve((size_t)M * 128 * 4);
    unsigned short* hb16  = (unsigned short*)hbuf;     // enc bf16 out (row-major); dead before dec writes hbuf
    unsigned short* aln16 = aggl;                      // LN'd bf16 A (fragment-major); live only while aggl dead
    int2*  tmpD = (int2*)e0;                           // bucket-grouped entries (graph build only)
    int2*  tmpS = (int2*)e1;

    float* outf      = (float*)d_out;
    float* score     = outf;                                   // [M,2]
    float* edge_feat = outf + (size_t)M * 2;                   // [M,128]
    float* node_feat = outf + (size_t)M * 2 + (size_t)M * 128; // [N,128]

    // ---- fused weight prep (transpose + split-bf16, fragment-major)
    k_prepAll<<<1024, 256, 0, stream>>>(eW, dW, W1, encTh, encTl, decTh, decTl, w1Th, w1Tl);

    // ---- graph structure: bucket count -> bucket scan(+cursors) -> partition -> per-bucket rowptr+CSR place
    hipMemsetAsync(minv, 0x7f, 4, stream);
    hipMemsetAsync(bcD, 0, (size_t)nbD * 4, stream);
    hipMemsetAsync(bcS, 0, (size_t)nbS * 4, stream);
    hipMemsetAsync(stats, 0, 16 * 132 * 4, stream);   // banked stats zeroed ONCE; k_finalize re-zeroes after each use
    k_min<<<256, 256, 0, stream>>>(dstE, E, minv);
    k_bcount<<<(E + BC_CHUNK - 1) / BC_CHUNK, 256, 0, stream>>>(dstE, srcN, minv, E, nbD, nbS, bcD, bcS);
    k_scan<<<1, 1024, 0, stream>>>(bcD, nbD, bbD, curD);
    k_scan<<<1, 1024, 0, stream>>>(bcS, nbS, bbS, curS);
    k_part<<<(E + PART_CHUNK - 1) / PART_CHUNK, 256, 0, stream>>>(
        dstE, srcN, norm, minv, E, nbD, nbS, curD, curS, tmpD, tmpS);
    k_place<<<nbD, 256, 0, stream>>>(tmpD, bbD, M, nbD, pairD, rpM);
    k_place<<<nbS, 256, 0, stream>>>(tmpS, bbS, N, nbS, pairS, rpN);

    // ---- matmul dispatch helpers
    auto mmenc = [&](int rows, int k) {
        if (rows > 30000)
            k_mm16<0,0><<<(rows + 31) / 32, 256, 0, stream>>>(
                aln16, nullptr, rows, encTh + (size_t)k * 16384, encTl + (size_t)k * 16384,
                eB + (size_t)k * 128, hb16, nullptr);
        else
            k_mm16<1,0><<<(rows + 15) / 16, 256, 0, stream>>>(
                aln16, nullptr, rows, encTh + (size_t)k * 16384, encTl + (size_t)k * 16384,
                eB + (size_t)k * 128, hb16, nullptr);
    };
    auto mmdec = [&](int rows, int k) {
        if (rows > 30000)
            k_mm16<0,1><<<(rows + 31) / 32, 256, 0, stream>>>(
                aggh, aggl, rows, decTh + (size_t)k * 16384, decTl + (size_t)k * 16384,
                dB + (size_t)k * 128, hbuf, stats);
        else
            k_mm16<1,1><<<(rows + 15) / 16, 256, 0, stream>>>(
                aggh, aggl, rows, decTh + (size_t)k * 16384, decTl + (size_t)k * 16384,
                dB + (size_t)k * 128, hbuf, stats);
    };

    // ---- one half-conv: enc(bf16 A) -> CSR-mean agg (split hi/lo) -> dec(fused stats) -> rowprep tail
    auto conv = [&](int S, int T, int k, int v2e, float* dest) {
        mmenc(S, k);
        if (v2e)
            k_aggregate<4><<<(T + 3) / 4, 256, 0, stream>>>(hb16, rpM, pairD, aggh, aggl, T);
        else
            k_aggregate<1><<<(T + 15) / 16, 256, 0, stream>>>(hb16, rpN, pairS, aggh, aggl, T);
        mmdec(T, k);
        k_finalize<<<1, 128, 0, stream>>>(stats, fstat, T);
        if (k < 4) {
            // fused: center_scale -> dest (skipped if dead), then preop+LN+bf16 for conv k+1's enc A
            k_rowprep<<<(T + 15) / 16, 256, 0, stream>>>(
                hbuf, T, fstat, dest, 1,
                elng + (size_t)(k + 1) * 128, elnb + (size_t)(k + 1) * 128, aln16);
        } else {
            size_t tot4 = ((size_t)T * 128) / 4;
            k_apply<<<(unsigned)((tot4 + 255) / 256), 256, 0, stream>>>(hbuf, fstat, dest, T);
        }
    };

    // conv0's enc A from raw x (no preop, LN params k=0)
    k_rowprep<<<(N + 15) / 16, 256, 0, stream>>>(x, N, nullptr, nullptr, 0, elng, elnb, aln16);
    conv(N, M, 0, 1, e0);         // V2E0  (tail preps conv1's A at M rows)
    conv(M, N, 1, 0, nullptr);    // E2V0  (nf1 is dead — overwritten by conv3 before any read)
    conv(N, M, 2, 1, e1);         // V2E1
    conv(M, N, 3, 0, node_feat);  // E2V1 -> final node_feat
    conv(N, M, 4, 1, edge_feat);  // V2E2 -> final edge_feat (plain apply tail)

    k_cls<<<(M + 15) / 16, 256, 0, stream>>>(
        e0, e1, edge_feat, w1Th, w1Tl, b1, clng, clnb, W2, b2, score, M);
}